// Round 3
// baseline (19676.437 us; speedup 1.0000x reference)
//
#include <hip/hip_runtime.h>

typedef __attribute__((ext_vector_type(8))) short bf16x8;
typedef __attribute__((ext_vector_type(4))) float f32x4;

#define NB 128
#define NT 64
#define ND 300
#define NH 512

__device__ __forceinline__ float4 ld4(const float* p) { return *(const float4*)p; }
__device__ __forceinline__ unsigned short f2bf(float x) {
  unsigned int u = __float_as_uint(x);
  u += 0x7FFF + ((u >> 16) & 1);
  return (unsigned short)(u >> 16);
}
__device__ __forceinline__ float bf2f(unsigned short h) {
  return __uint_as_float(((unsigned int)h) << 16);
}
__device__ __forceinline__ float tanh_fast(float x) {
  x = fminf(fmaxf(x, -15.f), 15.f);
  const float e = __expf(2.f * x);
  return (e - 1.f) / (e + 1.f);
}
__device__ __forceinline__ float sigm(float x) { return 1.f / (1.f + __expf(-x)); }

// ---- device-scope grid barrier (all WGs resident by construction) ----
__device__ __forceinline__ void gbar(int* bar, int nwg, int ord) {
  __threadfence();
  __syncthreads();
  if (threadIdx.x == 0) {
    int a = __hip_atomic_fetch_add(&bar[0], 1, __ATOMIC_ACQ_REL, __HIP_MEMORY_SCOPE_AGENT);
    if (a == nwg - 1) {
      __hip_atomic_store(&bar[0], 0, __ATOMIC_RELAXED, __HIP_MEMORY_SCOPE_AGENT);
      __hip_atomic_store(&bar[1], ord + 1, __ATOMIC_RELEASE, __HIP_MEMORY_SCOPE_AGENT);
    } else {
      int it = 0;
      while (__hip_atomic_load(&bar[1], __ATOMIC_ACQUIRE, __HIP_MEMORY_SCOPE_AGENT) < ord + 1) {
        __builtin_amdgcn_s_sleep(2);
        if (++it > (1 << 21)) break;  // bounded: fail loud, never hang
      }
    }
  }
  __syncthreads();
  __threadfence();
}

// ============ persistent LSTM scan: 4 runs x 64 steps, 1 barrier/step ============
// grid 512 = 2 weights x 4 mtiles(64 rows of 256) x 64 ntiles(8 hcols).
// B gate-interleaved col-major: col c of ntile nt -> gate g=c>>3, hcol=nt*8+(c&7).
__global__ __launch_bounds__(256, 2) void lstm_scan(
    const float* __restrict__ emb, const int* __restrict__ tok1, const int* __restrict__ tok2,
    const unsigned short* __restrict__ W1h, const unsigned short* __restrict__ W1l,
    const unsigned short* __restrict__ W2h, const unsigned short* __restrict__ W2l,
    const float* __restrict__ b1, const float* __restrict__ b2,
    const int* __restrict__ s1, const int* __restrict__ s2,
    unsigned int* __restrict__ hq, unsigned short* __restrict__ Yh,
    unsigned short* __restrict__ Yl, int* bar) {
  const int w = blockIdx.x;
  const int wgt = w & 1, mt = (w >> 1) & 3, nt = w >> 3;
  const int tid = threadIdx.x;
  const int wvi = tid >> 6, lane = tid & 63;
  const int fr = lane & 15, kg = (lane >> 4) << 3;

  __shared__ __align__(16) unsigned short Bh_s[32][840];
  __shared__ __align__(16) unsigned short As[2][64][40];
  __shared__ __align__(16) unsigned short Blo_s[32][40];
  __shared__ float Gs[64][33];

  const unsigned short* BhG = (wgt ? W2h : W1h) + (size_t)(nt * 32) * 832;
  const unsigned short* BloG = (wgt ? W2l : W1l) + (size_t)(nt * 32) * 832;
  for (int i = tid; i < 32 * 104; i += 256) {  // resident hi-plane: 32 cols x 832 k
    const int c = i / 104, o8 = (i % 104) * 8;
    *(bf16x8*)&Bh_s[c][o8] = *(const bf16x8*)&BhG[(size_t)c * 832 + o8];
  }

  // staging identity (row sr, k-octet sq)
  const int sr = tid >> 2, sq = tid & 3;
  const int gr = mt * 64 + sr;
  const int runS = (gr < 128) ? (wgt ? 1 : 0) : (wgt ? 3 : 2);
  const int bS = gr & 127;
  const int* tokS = (runS == 0 || runS == 3) ? tok1 : tok2;

  // update identity (row ur, hcol pair)
  const int ur = tid & 63, hcg = tid >> 6;
  const int gu = mt * 64 + ur;
  const int runU = (gu < 128) ? (wgt ? 1 : 0) : (wgt ? 3 : 2);
  const int bU = gu & 127;
  const int slU = ((runU == 0 || runU == 3) ? s1 : s2)[bU];
  const float* biasU = (runU & 1) ? b2 : b1;
  float bia[2][4];
  float c_reg[2] = {0.f, 0.f}, h_reg[2] = {0.f, 0.f};
#pragma unroll
  for (int e = 0; e < 2; ++e) {
    const int hc = hcg * 2 + e;
#pragma unroll
    for (int g = 0; g < 4; ++g) bia[e][g] = biasU[g * NH + nt * 8 + hc];
  }
  __syncthreads();

  for (int t = 0; t < NT; ++t) {
    const unsigned int* hrd = hq + (size_t)((t + 1) & 1) * (4 * NB * NH);
    const int token = tokS[bS * NT + t];
    f32x4 acc[2];
    acc[0] = 0.f; acc[1] = 0.f;
    for (int ch = 0; ch < 26; ++ch) {
      const int k8 = (ch << 5) + (sq << 3);
      bf16x8 ah, al;
      if (k8 < 320) {
        float va[8];
        if (k8 + 8 <= ND) {
          const float4 v1 = ld4(emb + (size_t)token * ND + k8);
          const float4 v2 = ld4(emb + (size_t)token * ND + k8 + 4);
          va[0] = v1.x; va[1] = v1.y; va[2] = v1.z; va[3] = v1.w;
          va[4] = v2.x; va[5] = v2.y; va[6] = v2.z; va[7] = v2.w;
        } else {
#pragma unroll
          for (int u = 0; u < 8; ++u) {
            const int k = k8 + u;
            va[u] = (k < ND) ? emb[(size_t)token * ND + k] : 0.f;
          }
        }
#pragma unroll
        for (int u = 0; u < 8; ++u) {
          const unsigned short hh = f2bf(va[u]);
          ah[u] = (short)hh;
          al[u] = (short)f2bf(va[u] - bf2f(hh));
        }
      } else {
        const unsigned int* hp = hrd + (size_t)(runS * NB + bS) * NH + (k8 - 320);
#pragma unroll
        for (int u = 0; u < 8; ++u) {
          const unsigned int pv = hp[u];
          ah[u] = (short)(pv >> 16);
          al[u] = (short)(pv & 0xFFFF);
        }
      }
      *(bf16x8*)&As[0][sr][sq << 3] = ah;
      *(bf16x8*)&As[1][sr][sq << 3] = al;
      if (tid < 128) {
        const int c = tid >> 2, o8 = (tid & 3) << 3;
        *(bf16x8*)&Blo_s[c][o8] = *(const bf16x8*)&BloG[(size_t)c * 832 + (ch << 5) + o8];
      }
      __syncthreads();
      const bf16x8 Ahf = *(const bf16x8*)&As[0][wvi * 16 + fr][kg];
      const bf16x8 Alf = *(const bf16x8*)&As[1][wvi * 16 + fr][kg];
#pragma unroll
      for (int ni = 0; ni < 2; ++ni) {
        const bf16x8 Bhf = *(const bf16x8*)&Bh_s[ni * 16 + fr][(ch << 5) + kg];
        const bf16x8 Blf = *(const bf16x8*)&Blo_s[ni * 16 + fr][kg];
        acc[ni] = __builtin_amdgcn_mfma_f32_16x16x32_bf16(Alf, Bhf, acc[ni], 0, 0, 0);
        acc[ni] = __builtin_amdgcn_mfma_f32_16x16x32_bf16(Ahf, Blf, acc[ni], 0, 0, 0);
        acc[ni] = __builtin_amdgcn_mfma_f32_16x16x32_bf16(Ahf, Bhf, acc[ni], 0, 0, 0);
      }
      __syncthreads();
    }
    // epilogue: gates -> LDS -> in-register c/h update
#pragma unroll
    for (int ni = 0; ni < 2; ++ni)
#pragma unroll
      for (int q = 0; q < 4; ++q)
        Gs[wvi * 16 + (lane >> 4) * 4 + q][ni * 16 + fr] = acc[ni][q];
    __syncthreads();
    unsigned int* hwr = hq + (size_t)(t & 1) * (4 * NB * NH);
    const bool vld = (t < slU);
#pragma unroll
    for (int e = 0; e < 2; ++e) {
      const int hc = hcg * 2 + e;
      const float gi = Gs[ur][hc] + bia[e][0];
      const float gj = Gs[ur][8 + hc] + bia[e][1];
      const float gf = Gs[ur][16 + hc] + bia[e][2];
      const float go = Gs[ur][24 + hc] + bia[e][3];
      const float cn = c_reg[e] * sigm(gf + 1.f) + sigm(gi) * tanh_fast(gj);
      const float hn = tanh_fast(cn) * sigm(go);
      float y = 0.f;
      if (vld) { c_reg[e] = cn; h_reg[e] = hn; y = hn; }
      const unsigned short hh = f2bf(h_reg[e]);
      const unsigned short hl = f2bf(h_reg[e] - bf2f(hh));
      hwr[(size_t)(runU * NB + bU) * NH + nt * 8 + hc] = (((unsigned int)hh) << 16) | hl;
      const unsigned short yh = f2bf(y);
      const unsigned short yl = f2bf(y - bf2f(yh));
      const size_t yi = ((size_t)(runU * NB + bU) * NT + t) * NH + nt * 8 + hc;
      Yh[yi] = yh; Yl[yi] = yl;
    }
    if (t < NT - 1) gbar(bar, 512, t);
  }
}

// ============ persistent attention scan: 2 asyms x 128 b, 64 steps ============
// grid 256. phase A: uv = r @ [Wr|Wt] (tiles 64r x 16c, Wrt LDS-resident);
// phase B: WG p = pair (a,b): scores/softmax/Y@alpha/r-update.
__global__ __launch_bounds__(256, 2) void attn_scan(
    const unsigned short* __restrict__ Wrth, const unsigned short* __restrict__ Wrtl,
    const float* __restrict__ WyY, const float* __restrict__ WhY2,
    const unsigned short* __restrict__ Yh, const float* __restrict__ wvp,
    const int* __restrict__ s1, const int* __restrict__ s2,
    unsigned int* __restrict__ rq, float* __restrict__ uv, float* __restrict__ rfin,
    int* bar) {
  const int q = blockIdx.x;
  const int mtq = q >> 6, ntq = q & 63;
  const int tid = threadIdx.x;
  const int wvi = tid >> 6, lane = tid & 63;
  const int fr = lane & 15, kg = (lane >> 4) << 3;

  __shared__ __align__(16) unsigned short Bh2[16][520];
  __shared__ __align__(16) unsigned short Bl2[16][520];
  __shared__ __align__(16) unsigned short As2[2][64][40];
  __shared__ float4 u4s[128], w4s[128];
  __shared__ float s_sh[NT], al_sh[NT];

  for (int i = tid; i < 16 * 64; i += 256) {  // resident Wrt tile: 16 cols x 512 k
    const int c = i >> 6, o8 = (i & 63) << 3;
    *(bf16x8*)&Bh2[c][o8] = *(const bf16x8*)&Wrth[(size_t)(ntq * 16 + c) * NH + o8];
    *(bf16x8*)&Bl2[c][o8] = *(const bf16x8*)&Wrtl[(size_t)(ntq * 16 + c) * NH + o8];
  }
  const int sr = tid >> 2, sq = tid & 3;
  const int gr2 = mtq * 64 + sr;
  // mix identity
  const int p = q, a = p >> 7, b = p & 127;
  const int sl = (a ? s2 : s1)[b];
  const int snap = (a ? s1 : s2)[b] - 1;
  const float* wyb = WyY + (size_t)(a * NB + b) * NT * NH;
  const unsigned short* Yp = Yh + (size_t)((a ? 2 : 0) * NB + b) * NT * NH;
  __syncthreads();

  for (int t = 0; t < NT; ++t) {
    // ---- phase A: uv tile ----
    {
      const unsigned int* rrd = rq + (size_t)((t + 1) & 1) * (256 * NH);
      f32x4 acc;
      acc = 0.f;
      for (int ch = 0; ch < 16; ++ch) {
        const int k8 = (ch << 5) + (sq << 3);
        const unsigned int* hp = rrd + (size_t)gr2 * NH + k8;
        bf16x8 ah, al;
#pragma unroll
        for (int u = 0; u < 8; ++u) {
          const unsigned int pv = hp[u];
          ah[u] = (short)(pv >> 16);
          al[u] = (short)(pv & 0xFFFF);
        }
        *(bf16x8*)&As2[0][sr][sq << 3] = ah;
        *(bf16x8*)&As2[1][sr][sq << 3] = al;
        __syncthreads();
        const bf16x8 Ahf = *(const bf16x8*)&As2[0][wvi * 16 + fr][kg];
        const bf16x8 Alf = *(const bf16x8*)&As2[1][wvi * 16 + fr][kg];
        const bf16x8 Bhf = *(const bf16x8*)&Bh2[fr][(ch << 5) + kg];
        const bf16x8 Blf = *(const bf16x8*)&Bl2[fr][(ch << 5) + kg];
        acc = __builtin_amdgcn_mfma_f32_16x16x32_bf16(Alf, Bhf, acc, 0, 0, 0);
        acc = __builtin_amdgcn_mfma_f32_16x16x32_bf16(Ahf, Blf, acc, 0, 0, 0);
        acc = __builtin_amdgcn_mfma_f32_16x16x32_bf16(Ahf, Bhf, acc, 0, 0, 0);
        __syncthreads();
      }
#pragma unroll
      for (int qq = 0; qq < 4; ++qq) {
        const int row = mtq * 64 + wvi * 16 + (lane >> 4) * 4 + qq;
        uv[(size_t)row * 1024 + ntq * 16 + fr] = acc[qq];
      }
    }
    gbar(bar, 256, 2 * t);
    // ---- phase B: mix for pair p ----
    {
      if (tid < 128) {
        const float4 x = ld4(WhY2 + ((size_t)(a * NB + b) * NT + t) * NH + tid * 4);
        const float4 y = ld4(uv + (size_t)p * 1024 + tid * 4);
        u4s[tid] = make_float4(x.x + y.x, x.y + y.y, x.z + y.z, x.w + y.w);
        w4s[tid] = ld4(wvp + tid * 4);
      }
      __syncthreads();
      for (int tp = wvi; tp < NT; tp += 4) {
        float pt = 0.f;
        if (tp < sl) {
          const float* row = wyb + (size_t)tp * NH;
#pragma unroll
          for (int j2 = 0; j2 < 2; ++j2) {
            const int j = lane + (j2 << 6);
            const float4 x = ld4(row + j * 4);
            const float4 u = u4s[j], ww = w4s[j];
            pt += tanh_fast(x.x + u.x) * ww.x + tanh_fast(x.y + u.y) * ww.y
                + tanh_fast(x.z + u.z) * ww.z + tanh_fast(x.w + u.w) * ww.w;
          }
          for (int off = 32; off; off >>= 1) pt += __shfl_xor(pt, off, 64);
        }
        if (lane == 0) s_sh[tp] = (tp < sl) ? pt : -1e30f;
      }
      __syncthreads();
      if (tid < NT) {
        const float sv = s_sh[tid];
        float mx = sv;
        for (int off = 32; off; off >>= 1) mx = fmaxf(mx, __shfl_xor(mx, off, 64));
        const float e = (tid < sl) ? __expf(sv - mx) : 0.f;
        float sm = e;
        for (int off = 32; off; off >>= 1) sm += __shfl_xor(sm, off, 64);
        al_sh[tid] = e / sm;
      }
      __syncthreads();
      unsigned int* rwr = rq + (size_t)(t & 1) * (256 * NH);
#pragma unroll
      for (int q2 = 0; q2 < 2; ++q2) {
        const int hh = tid + (q2 << 8);
        float ya = 0.f;
        for (int tp = 0; tp < sl; ++tp) ya += al_sh[tp] * bf2f(Yp[(size_t)tp * NH + hh]);
        const float rn = ya + tanh_fast(uv[(size_t)p * 1024 + NH + hh]);
        const unsigned short rh = f2bf(rn);
        const unsigned short rl = f2bf(rn - bf2f(rh));
        rwr[(size_t)p * NH + hh] = (((unsigned int)rh) << 16) | rl;
        if (t == snap) rfin[(size_t)p * NH + hh] = rn;
      }
    }
    if (t < NT - 1) gbar(bar, 256, 2 * t + 1);
  }
}

// ============ WyY / WhY2: Y(runs) @ Wy/Wh, 64x64 tile, parallel ============
__global__ __launch_bounds__(256) void gemm_yw(
    const unsigned short* __restrict__ Yh, const unsigned short* __restrict__ Yl,
    const unsigned short* __restrict__ Wyh, const unsigned short* __restrict__ Wyl,
    const unsigned short* __restrict__ Whh, const unsigned short* __restrict__ Whl,
    float* __restrict__ WyY, float* __restrict__ WhY2) {
  const int n0 = blockIdx.x << 6, m0 = blockIdx.y << 6, z = blockIdx.z;
  const int runsel = (z == 0) ? 0 : (z == 1) ? 2 : (z == 2) ? 1 : 3;
  const unsigned short* Bh = (z < 2) ? Wyh : Whh;
  const unsigned short* Bl = (z < 2) ? Wyl : Whl;
  float* Cd = (z < 2) ? (WyY + (size_t)z * (NB * NT * NH)) : (WhY2 + (size_t)(z - 2) * (NB * NT * NH));
  const int tid = threadIdx.x;
  const int wave = tid >> 6, lane = tid & 63;
  const int wm = wave >> 1, wn = wave & 1;
  const int fr = lane & 15, kg = (lane >> 4) << 3;
  __shared__ __align__(16) unsigned short As[2][64][40];
  __shared__ __align__(16) unsigned short Bs[2][64][40];
  const int sr = tid >> 2, sq = tid & 3;
  f32x4 acc[2][2];
#pragma unroll
  for (int mi = 0; mi < 2; ++mi)
#pragma unroll
    for (int ni = 0; ni < 2; ++ni) acc[mi][ni] = 0.f;
  const size_t arow = (size_t)runsel * (NB * NT) + m0 + sr;
  for (int ch = 0; ch < 16; ++ch) {
    const int k8 = (ch << 5) + (sq << 3);
    const bf16x8 ah = *(const bf16x8*)&Yh[arow * NH + k8];
    const bf16x8 al = *(const bf16x8*)&Yl[arow * NH + k8];
    const bf16x8 bh = *(const bf16x8*)&Bh[(size_t)(n0 + sr) * NH + k8];
    const bf16x8 bl = *(const bf16x8*)&Bl[(size_t)(n0 + sr) * NH + k8];
    __syncthreads();
    *(bf16x8*)&As[0][sr][sq << 3] = ah;
    *(bf16x8*)&As[1][sr][sq << 3] = al;
    *(bf16x8*)&Bs[0][sr][sq << 3] = bh;
    *(bf16x8*)&Bs[1][sr][sq << 3] = bl;
    __syncthreads();
    bf16x8 Afh[2], Afl[2], Bfh[2], Bfl[2];
#pragma unroll
    for (int mi = 0; mi < 2; ++mi) {
      Afh[mi] = *(const bf16x8*)&As[0][wm * 32 + mi * 16 + fr][kg];
      Afl[mi] = *(const bf16x8*)&As[1][wm * 32 + mi * 16 + fr][kg];
    }
#pragma unroll
    for (int ni = 0; ni < 2; ++ni) {
      Bfh[ni] = *(const bf16x8*)&Bs[0][wn * 32 + ni * 16 + fr][kg];
      Bfl[ni] = *(const bf16x8*)&Bs[1][wn * 32 + ni * 16 + fr][kg];
    }
#pragma unroll
    for (int mi = 0; mi < 2; ++mi)
#pragma unroll
      for (int ni = 0; ni < 2; ++ni) {
        acc[mi][ni] = __builtin_amdgcn_mfma_f32_16x16x32_bf16(Afl[mi], Bfh[ni], acc[mi][ni], 0, 0, 0);
        acc[mi][ni] = __builtin_amdgcn_mfma_f32_16x16x32_bf16(Afh[mi], Bfl[ni], acc[mi][ni], 0, 0, 0);
        acc[mi][ni] = __builtin_amdgcn_mfma_f32_16x16x32_bf16(Afh[mi], Bfh[ni], acc[mi][ni], 0, 0, 0);
      }
  }
#pragma unroll
  for (int mi = 0; mi < 2; ++mi)
#pragma unroll
    for (int ni = 0; ni < 2; ++ni) {
      const int row0 = m0 + wm * 32 + mi * 16 + ((lane >> 4) << 2);
      const int col = n0 + wn * 32 + ni * 16 + fr;
#pragma unroll
      for (int r = 0; r < 4; ++r)
        Cd[(size_t)(row0 + r) * NH + col] = acc[mi][ni][r];
    }
}

// ============ la/lb = tanh([rfin | last_h] @ [Wp;Wx]) ============
__global__ __launch_bounds__(256) void gemm_fin(
    const float* __restrict__ rfin, const unsigned int* __restrict__ hq1,
    const unsigned short* __restrict__ Wpxh, const unsigned short* __restrict__ Wpxl,
    float* __restrict__ lalb) {
  const int n0 = blockIdx.x << 6, m0 = blockIdx.y << 6;
  const int tid = threadIdx.x;
  const int wave = tid >> 6, lane = tid & 63;
  const int wm = wave >> 1, wn = wave & 1;
  const int fr = lane & 15, kg = (lane >> 4) << 3;
  __shared__ __align__(16) unsigned short As[2][64][40];
  __shared__ __align__(16) unsigned short Bs[2][64][40];
  const int sr = tid >> 2, sq = tid & 3;
  const int r_g = m0 + sr;
  const int run = r_g >> 7, bb = r_g & 127;
  f32x4 acc[2][2];
#pragma unroll
  for (int mi = 0; mi < 2; ++mi)
#pragma unroll
    for (int ni = 0; ni < 2; ++ni) acc[mi][ni] = 0.f;
  for (int ch = 0; ch < 32; ++ch) {
    const int k8 = (ch << 5) + (sq << 3);
    bf16x8 ah, al;
    if (k8 < NH) {
      const float4 v1 = ld4(rfin + (size_t)r_g * NH + k8);
      const float4 v2 = ld4(rfin + (size_t)r_g * NH + k8 + 4);
      float va[8] = {v1.x, v1.y, v1.z, v1.w, v2.x, v2.y, v2.z, v2.w};
#pragma unroll
      for (int u = 0; u < 8; ++u) {
        const unsigned short hh = f2bf(va[u]);
        ah[u] = (short)hh;
        al[u] = (short)f2bf(va[u] - bf2f(hh));
      }
    } else {
      const unsigned int* hp = hq1 + (size_t)((run ? 3 : 1) * NB + bb) * NH + (k8 - NH);
#pragma unroll
      for (int u = 0; u < 8; ++u) {
        const unsigned int pv = hp[u];
        ah[u] = (short)(pv >> 16);
        al[u] = (short)(pv & 0xFFFF);
      }
    }
    const bf16x8 bh = *(const bf16x8*)&Wpxh[(size_t)(n0 + sr) * 1024 + k8];
    const bf16x8 bl = *(const bf16x8*)&Wpxl[(size_t)(n0 + sr) * 1024 + k8];
    __syncthreads();
    *(bf16x8*)&As[0][sr][sq << 3] = ah;
    *(bf16x8*)&As[1][sr][sq << 3] = al;
    *(bf16x8*)&Bs[0][sr][sq << 3] = bh;
    *(bf16x8*)&Bs[1][sr][sq << 3] = bl;
    __syncthreads();
    bf16x8 Afh[2], Afl[2], Bfh[2], Bfl[2];
#pragma unroll
    for (int mi = 0; mi < 2; ++mi) {
      Afh[mi] = *(const bf16x8*)&As[0][wm * 32 + mi * 16 + fr][kg];
      Afl[mi] = *(const bf16x8*)&As[1][wm * 32 + mi * 16 + fr][kg];
    }
#pragma unroll
    for (int ni = 0; ni < 2; ++ni) {
      Bfh[ni] = *(const bf16x8*)&Bs[0][wn * 32 + ni * 16 + fr][kg];
      Bfl[ni] = *(const bf16x8*)&Bs[1][wn * 32 + ni * 16 + fr][kg];
    }
#pragma unroll
    for (int mi = 0; mi < 2; ++mi)
#pragma unroll
      for (int ni = 0; ni < 2; ++ni) {
        acc[mi][ni] = __builtin_amdgcn_mfma_f32_16x16x32_bf16(Afl[mi], Bfh[ni], acc[mi][ni], 0, 0, 0);
        acc[mi][ni] = __builtin_amdgcn_mfma_f32_16x16x32_bf16(Afh[mi], Bfl[ni], acc[mi][ni], 0, 0, 0);
        acc[mi][ni] = __builtin_amdgcn_mfma_f32_16x16x32_bf16(Afh[mi], Bfh[ni], acc[mi][ni], 0, 0, 0);
      }
  }
#pragma unroll
  for (int mi = 0; mi < 2; ++mi)
#pragma unroll
    for (int ni = 0; ni < 2; ++ni) {
      const int row0 = m0 + wm * 32 + mi * 16 + ((lane >> 4) << 2);
      const int col = n0 + wn * 32 + ni * 16 + fr;
#pragma unroll
      for (int r = 0; r < 4; ++r)
        lalb[(size_t)(row0 + r) * NH + col] = tanh_fast(acc[mi][ni][r]);
    }
}

// ============ pack: bf16 hi/lo splits ============
__global__ void pack_k(
    const float* __restrict__ W1, const float* __restrict__ W2,
    const float* __restrict__ Wy, const float* __restrict__ Wh,
    const float* __restrict__ Wr, const float* __restrict__ Wt,
    const float* __restrict__ Wp, const float* __restrict__ Wx,
    unsigned short* W1h, unsigned short* W1l, unsigned short* W2h, unsigned short* W2l,
    unsigned short* Wyh, unsigned short* Wyl, unsigned short* Whh, unsigned short* Whl,
    unsigned short* Wrth, unsigned short* Wrtl, unsigned short* Wpxh, unsigned short* Wpxl) {
  const int idx = blockIdx.x * 256 + threadIdx.x;
  const int SZW = 2048 * 832, SZS = 512 * 512, SZR = 1024 * 512, SZP = 512 * 1024;
  float v = 0.f; unsigned short *dh, *dl; int di;
  if (idx < 2 * SZW) {
    const float* W = (idx < SZW) ? W1 : W2;
    di = (idx < SZW) ? idx : idx - SZW;
    const int col = di / 832, k = di % 832;
    const int nt = col >> 5, c = col & 31;
    const int srcc = (c >> 3) * NH + (nt << 3) + (c & 7);  // gate-interleaved
    if (k < ND) v = W[(size_t)k * 2048 + srcc];
    else if (k >= 320) v = W[(size_t)(k - 20) * 2048 + srcc];
    dh = (idx < SZW) ? W1h : W2h; dl = (idx < SZW) ? W1l : W2l;
  } else if (idx < 2 * SZW + 2 * SZS) {
    const int i2 = idx - 2 * SZW;
    const float* W = (i2 < SZS) ? Wy : Wh;
    di = (i2 < SZS) ? i2 : i2 - SZS;
    const int n = di >> 9, k = di & 511;
    v = W[(size_t)k * NH + n];
    dh = (i2 < SZS) ? Wyh : Whh; dl = (i2 < SZS) ? Wyl : Whl;
  } else if (idx < 2 * SZW + 2 * SZS + SZR) {
    di = idx - 2 * SZW - 2 * SZS;
    const int n = di >> 9, k = di & 511;
    v = (n < NH) ? Wr[(size_t)k * NH + n] : Wt[(size_t)k * NH + (n - NH)];
    dh = Wrth; dl = Wrtl;
  } else {
    di = idx - 2 * SZW - 2 * SZS - SZR;
    const int n = di >> 10, k = di & 1023;
    v = (k < NH) ? Wp[(size_t)k * NH + n] : Wx[(size_t)(k - NH) * NH + n];
    dh = Wpxh; dl = Wpxl;
  }
  const unsigned short h = f2bf(v);
  dh[di] = h;
  dl[di] = f2bf(v - bf2f(h));
}

__global__ void out_k(const float* __restrict__ lalb, const float* __restrict__ U,
                      const float* __restrict__ bU, float* __restrict__ out) {
  const int tid = threadIdx.x;
  const int b = tid >> 1, j = tid & 1;
  float s = bU[j];
  for (int h = 0; h < NH; ++h)
    s += (lalb[b * NH + h] + lalb[NB * NH + b * NH + h]) * U[h * 2 + j];
  out[b * 2 + j] = s;
}

extern "C" void kernel_launch(void* const* d_in, const int* in_sizes, int n_in,
                              void* d_out, int out_size, void* d_ws, size_t ws_size,
                              hipStream_t stream) {
  const int* tok1 = (const int*)d_in[0];
  const int* tok2 = (const int*)d_in[1];
  const int* s1   = (const int*)d_in[2];
  const int* s2   = (const int*)d_in[3];
  const float* emb = (const float*)d_in[4];
  const float* W1 = (const float*)d_in[5];
  const float* b1 = (const float*)d_in[6];
  const float* W2 = (const float*)d_in[7];
  const float* b2 = (const float*)d_in[8];
  const float* Wy = (const float*)d_in[9];
  const float* Wh = (const float*)d_in[10];
  const float* Wr = (const float*)d_in[11];
  const float* wv = (const float*)d_in[12];
  const float* Wt = (const float*)d_in[13];
  const float* Wp = (const float*)d_in[14];
  const float* Wx = (const float*)d_in[15];
  const float* U  = (const float*)d_in[16];
  const float* bU = (const float*)d_in[17];

  float* ws = (float*)d_ws;
  // layout (float units)
  unsigned int* hq = (unsigned int*)ws;                 // 2 x 262144
  unsigned int* rq = hq + 524288;                       // 2 x 131072
  int* bar = (int*)(rq + 262144);                       // 64 ints
  float* uv   = (float*)(bar + 64);                     // 262144
  float* rfin = uv + 262144;                            // 131072
  float* lalb = rfin + 131072;                          // 131072
  float* WyY  = lalb + 131072;                          // 8388608
  float* WhY2 = WyY + 8388608;                          // 8388608
  unsigned short* Yh = (unsigned short*)(WhY2 + 8388608);  // 16777216 us
  unsigned short* Yl = Yh + 16777216;                   // 16777216 us
  unsigned short* W1h = Yl + 16777216;                  // 1703936 us each:
  unsigned short* W1l = W1h + 1703936;
  unsigned short* W2h = W1l + 1703936;
  unsigned short* W2l = W2h + 1703936;
  unsigned short* Wyh = W2l + 1703936;                  // 262144 us each:
  unsigned short* Wyl = Wyh + 262144;
  unsigned short* Whh = Wyl + 262144;
  unsigned short* Whl = Whh + 262144;
  unsigned short* Wrth = Whl + 262144;                  // 524288 us each:
  unsigned short* Wrtl = Wrth + 524288;
  unsigned short* Wpxh = Wrtl + 524288;
  unsigned short* Wpxl = Wpxh + 524288;

  // zero h/r state planes + barrier counters
  hipMemsetAsync(d_ws, 0, (size_t)(524288 + 262144 + 64) * 4, stream);
  pack_k<<<19456, 256, 0, stream>>>(W1, W2, Wy, Wh, Wr, Wt, Wp, Wx,
                                    W1h, W1l, W2h, W2l, Wyh, Wyl, Whh, Whl,
                                    Wrth, Wrtl, Wpxh, Wpxl);

  lstm_scan<<<512, 256, 0, stream>>>(emb, tok1, tok2, W1h, W1l, W2h, W2l,
                                     b1, b2, s1, s2, hq, Yh, Yl, bar);

  gemm_yw<<<dim3(8, 128, 4), 256, 0, stream>>>(Yh, Yl, Wyh, Wyl, Whh, Whl, WyY, WhY2);

  attn_scan<<<256, 256, 0, stream>>>(Wrth, Wrtl, WyY, WhY2, Yh, wv, s1, s2,
                                     rq, uv, rfin, bar + 8);

  gemm_fin<<<dim3(8, 4, 1), 256, 0, stream>>>(rfin, hq + 262144, Wpxh, Wpxl, lalb);
  out_k<<<1, 256, 0, stream>>>(lalb, U, bU, (float*)d_out);
}

// Round 4
// 3716.119 us; speedup vs baseline: 5.2949x; 5.2949x over previous
//
#include <hip/hip_runtime.h>

typedef __attribute__((ext_vector_type(8))) short bf16x8;
typedef __attribute__((ext_vector_type(4))) float f32x4;
typedef unsigned short us;
typedef unsigned int u32;

#define NB 128
#define NT 64
#define ND 300
#define NH 512
#define KW 832   // padded LSTM K: 320 (emb) + 512 (h)

__device__ __forceinline__ float4 ld4(const float* p) { return *(const float4*)p; }
__device__ __forceinline__ us f2bf(float x) {
  u32 u = __float_as_uint(x);
  u += 0x7FFF + ((u >> 16) & 1);
  return (us)(u >> 16);
}
__device__ __forceinline__ float bf2f(us h) {
  return __uint_as_float(((u32)h) << 16);
}
__device__ __forceinline__ float tanh_fast(float x) {
  x = fminf(fmaxf(x, -15.f), 15.f);
  const float e = __expf(2.f * x);
  return (e - 1.f) / (e + 1.f);
}
__device__ __forceinline__ float sigm(float x) { return 1.f / (1.f + __expf(-x)); }

// ================= fused LSTM step: gates GEMM + pointwise update =================
// grid 256 (XCD-swizzled): nt in [0,32) (16 h-cols each, gate-interleaved), mt in [0,8).
// B packed [col][k]: col c of tile nt -> gate (c&63)>>4, hcol nt*16 + (c&15).
__global__ __launch_bounds__(256) void lstm_step(
    const float* __restrict__ emb, const int* __restrict__ tok1, const int* __restrict__ tok2,
    const us* __restrict__ W1h, const us* __restrict__ W1l,
    const us* __restrict__ W2h, const us* __restrict__ W2l,
    const float* __restrict__ b1, const float* __restrict__ b2,
    const int* __restrict__ s1, const int* __restrict__ s2,
    u32* __restrict__ hq, float* __restrict__ cbuf,
    us* __restrict__ Yh, us* __restrict__ Yl, int t) {
  const int bid = blockIdx.x;
  const int nt = (bid & 7) * 4 + ((bid >> 3) & 3);   // same nt -> same XCD each launch
  const int mt = bid >> 5;
  const int n0 = nt << 6, m0 = mt << 6;
  const int tid = threadIdx.x;
  const int wave = tid >> 6, lane = tid & 63;
  const int wm = wave >> 1, wn = wave & 1;
  const int fr = lane & 15, kg = (lane >> 4) << 3;

  __shared__ __align__(16) us As[2][64][40];
  __shared__ __align__(16) us Bs[2][64][40];
  __shared__ float Gs[64][65];

  const int sr = tid >> 2, sq = tid & 3;
  const int rg = m0 + sr;
  const int run = rg >> 7, bb = rg & 127;   // block lies within one run
  const int token = ((run == 0 || run == 3) ? tok1 : tok2)[bb * NT + t];
  const us* Bh = (run & 1) ? W2h : W1h;
  const us* Bl = (run & 1) ? W2l : W1l;
  const u32* hrd = hq + (size_t)((t + 1) & 1) * (4 * NB * NH);

  f32x4 acc[2][2];
#pragma unroll
  for (int mi = 0; mi < 2; ++mi)
#pragma unroll
    for (int ni = 0; ni < 2; ++ni) acc[mi][ni] = 0.f;

  for (int ch = 0; ch < 26; ++ch) {
    const int k8 = (ch << 5) + (sq << 3);
    bf16x8 ah, al;
    if (k8 < 320) {
      float va[8];
#pragma unroll
      for (int g2 = 0; g2 < 2; ++g2) {
        const int k4 = k8 + (g2 << 2);
        float4 v = make_float4(0.f, 0.f, 0.f, 0.f);
        if (k4 < ND) v = ld4(emb + (size_t)token * ND + k4);   // 300 % 4 == 0: exact
        va[g2 * 4 + 0] = v.x; va[g2 * 4 + 1] = v.y; va[g2 * 4 + 2] = v.z; va[g2 * 4 + 3] = v.w;
      }
#pragma unroll
      for (int u = 0; u < 8; ++u) {
        const us h = f2bf(va[u]);
        ah[u] = (short)h;
        al[u] = (short)f2bf(va[u] - bf2f(h));
      }
    } else {
      const u32* hp = hrd + (size_t)(run * NB + bb) * NH + (k8 - 320);
#pragma unroll
      for (int u = 0; u < 8; ++u) {
        const u32 pv = hp[u];
        ah[u] = (short)(pv >> 16);
        al[u] = (short)(pv & 0xFFFF);
      }
    }
    const size_t boff = (size_t)(n0 + sr) * KW + k8;
    const bf16x8 bvh = *(const bf16x8*)(Bh + boff);
    const bf16x8 bvl = *(const bf16x8*)(Bl + boff);

    __syncthreads();
    *(bf16x8*)&As[0][sr][sq << 3] = ah;
    *(bf16x8*)&As[1][sr][sq << 3] = al;
    *(bf16x8*)&Bs[0][sr][sq << 3] = bvh;
    *(bf16x8*)&Bs[1][sr][sq << 3] = bvl;
    __syncthreads();

    bf16x8 Afh[2], Afl[2], Bfh[2], Bfl[2];
#pragma unroll
    for (int mi = 0; mi < 2; ++mi) {
      Afh[mi] = *(const bf16x8*)&As[0][wm * 32 + mi * 16 + fr][kg];
      Afl[mi] = *(const bf16x8*)&As[1][wm * 32 + mi * 16 + fr][kg];
    }
#pragma unroll
    for (int ni = 0; ni < 2; ++ni) {
      Bfh[ni] = *(const bf16x8*)&Bs[0][wn * 32 + ni * 16 + fr][kg];
      Bfl[ni] = *(const bf16x8*)&Bs[1][wn * 32 + ni * 16 + fr][kg];
    }
#pragma unroll
    for (int mi = 0; mi < 2; ++mi)
#pragma unroll
      for (int ni = 0; ni < 2; ++ni) {
        acc[mi][ni] = __builtin_amdgcn_mfma_f32_16x16x32_bf16(Afl[mi], Bfh[ni], acc[mi][ni], 0, 0, 0);
        acc[mi][ni] = __builtin_amdgcn_mfma_f32_16x16x32_bf16(Afh[mi], Bfl[ni], acc[mi][ni], 0, 0, 0);
        acc[mi][ni] = __builtin_amdgcn_mfma_f32_16x16x32_bf16(Afh[mi], Bfh[ni], acc[mi][ni], 0, 0, 0);
      }
  }

  // gates -> LDS (transpose out of MFMA layout)
#pragma unroll
  for (int mi = 0; mi < 2; ++mi)
#pragma unroll
    for (int ni = 0; ni < 2; ++ni) {
      const int r0 = wm * 32 + mi * 16 + ((lane >> 4) << 2);
      const int cc = wn * 32 + ni * 16 + fr;
#pragma unroll
      for (int r = 0; r < 4; ++r) Gs[r0 + r][cc] = acc[mi][ni][r];
    }
  __syncthreads();

  // fused pointwise update: thread (ur, hg) handles 4 h-cols
  const int ur = tid & 63, hg = tid >> 6;
  const int gu = m0 + ur;
  const int runU = gu >> 7, bU = gu & 127;
  const int slU = ((runU == 0 || runU == 3) ? s1 : s2)[bU];
  const float* bias = (runU & 1) ? b2 : b1;
  const bool vld = t < slU;
  u32* hwr = hq + (size_t)(t & 1) * (4 * NB * NH);

  const int hcb = hg << 2;             // 0,4,8,12 within tile
  const int ghb = nt * 16 + hcb;       // global h col base
  const size_t so = (size_t)(runU * NB + bU) * NH + ghb;
  const float4 bi4 = ld4(bias + ghb);
  const float4 bj4 = ld4(bias + NH + ghb);
  const float4 bf4 = ld4(bias + 2 * NH + ghb);
  const float4 bo4 = ld4(bias + 3 * NH + ghb);
  const float4 c4 = ld4(cbuf + so);
  const uint4 hv4 = *(const uint4*)(hrd + so);
  const float bia[4] = {bi4.x, bi4.y, bi4.z, bi4.w};
  const float bja[4] = {bj4.x, bj4.y, bj4.z, bj4.w};
  const float bfa[4] = {bf4.x, bf4.y, bf4.z, bf4.w};
  const float boa[4] = {bo4.x, bo4.y, bo4.z, bo4.w};
  const float ca[4] = {c4.x, c4.y, c4.z, c4.w};
  const u32 ha[4] = {hv4.x, hv4.y, hv4.z, hv4.w};
  float cw[4]; u32 hw[4]; us yh4[4], yl4[4];
#pragma unroll
  for (int e = 0; e < 4; ++e) {
    const int hc = hcb + e;
    const float gi = Gs[ur][hc] + bia[e];
    const float gj = Gs[ur][16 + hc] + bja[e];
    const float gf = Gs[ur][32 + hc] + bfa[e];
    const float go = Gs[ur][48 + hc] + boa[e];
    const float hold = bf2f((us)(ha[e] >> 16)) + bf2f((us)(ha[e] & 0xFFFF));
    const float cn = ca[e] * sigm(gf + 1.f) + sigm(gi) * tanh_fast(gj);
    const float hn = tanh_fast(cn) * sigm(go);
    cw[e] = vld ? cn : ca[e];
    const float hval = vld ? hn : hold;
    const float y = vld ? hn : 0.f;
    const us hh = f2bf(hval);
    hw[e] = (((u32)hh) << 16) | f2bf(hval - bf2f(hh));
    yh4[e] = f2bf(y);
    yl4[e] = f2bf(y - bf2f(yh4[e]));
  }
  *(float4*)(cbuf + so) = make_float4(cw[0], cw[1], cw[2], cw[3]);
  *(uint4*)(hwr + so) = make_uint4(hw[0], hw[1], hw[2], hw[3]);
  const size_t yi = ((size_t)(runU * NB + bU) * NT + t) * NH + ghb;
  *(u32*)(Yh + yi) = ((u32)yh4[1] << 16) | yh4[0];
  *(u32*)(Yh + yi + 2) = ((u32)yh4[3] << 16) | yh4[2];
  *(u32*)(Yl + yi) = ((u32)yl4[1] << 16) | yl4[0];
  *(u32*)(Yl + yi + 2) = ((u32)yl4[3] << 16) | yl4[2];
}

// ================= uv = r @ [Wr|Wt], k-split x2, XCD-swizzled =================
__global__ __launch_bounds__(256) void uv_gemm(
    const us* __restrict__ Wrth, const us* __restrict__ Wrtl,
    const u32* __restrict__ rq, float* __restrict__ uv, int t) {
  const int bid = blockIdx.x;
  const int zk = bid >> 6, rem = bid & 63;
  const int nt = (rem & 7) * 2 + ((rem >> 3) & 1);
  const int mt = rem >> 4;
  const int n0 = nt << 6, m0 = mt << 6;
  const int tid = threadIdx.x;
  const int wave = tid >> 6, lane = tid & 63;
  const int wm = wave >> 1, wn = wave & 1;
  const int fr = lane & 15, kg = (lane >> 4) << 3;

  __shared__ __align__(16) us As[2][64][40];
  __shared__ __align__(16) us Bs[2][64][40];

  const int sr = tid >> 2, sq = tid & 3;
  const u32* rrd = rq + (size_t)((t + 1) & 1) * (256 * NH);

  f32x4 acc[2][2];
#pragma unroll
  for (int mi = 0; mi < 2; ++mi)
#pragma unroll
    for (int ni = 0; ni < 2; ++ni) acc[mi][ni] = 0.f;

  for (int ch = zk * 8; ch < zk * 8 + 8; ++ch) {
    const int k8 = (ch << 5) + (sq << 3);
    const u32* hp = rrd + (size_t)(m0 + sr) * NH + k8;
    bf16x8 ah, al;
#pragma unroll
    for (int u = 0; u < 8; ++u) {
      const u32 pv = hp[u];
      ah[u] = (short)(pv >> 16);
      al[u] = (short)(pv & 0xFFFF);
    }
    const size_t boff = (size_t)(n0 + sr) * NH + k8;
    const bf16x8 bvh = *(const bf16x8*)(Wrth + boff);
    const bf16x8 bvl = *(const bf16x8*)(Wrtl + boff);
    __syncthreads();
    *(bf16x8*)&As[0][sr][sq << 3] = ah;
    *(bf16x8*)&As[1][sr][sq << 3] = al;
    *(bf16x8*)&Bs[0][sr][sq << 3] = bvh;
    *(bf16x8*)&Bs[1][sr][sq << 3] = bvl;
    __syncthreads();
    bf16x8 Afh[2], Afl[2], Bfh[2], Bfl[2];
#pragma unroll
    for (int mi = 0; mi < 2; ++mi) {
      Afh[mi] = *(const bf16x8*)&As[0][wm * 32 + mi * 16 + fr][kg];
      Afl[mi] = *(const bf16x8*)&As[1][wm * 32 + mi * 16 + fr][kg];
    }
#pragma unroll
    for (int ni = 0; ni < 2; ++ni) {
      Bfh[ni] = *(const bf16x8*)&Bs[0][wn * 32 + ni * 16 + fr][kg];
      Bfl[ni] = *(const bf16x8*)&Bs[1][wn * 32 + ni * 16 + fr][kg];
    }
#pragma unroll
    for (int mi = 0; mi < 2; ++mi)
#pragma unroll
      for (int ni = 0; ni < 2; ++ni) {
        acc[mi][ni] = __builtin_amdgcn_mfma_f32_16x16x32_bf16(Afl[mi], Bfh[ni], acc[mi][ni], 0, 0, 0);
        acc[mi][ni] = __builtin_amdgcn_mfma_f32_16x16x32_bf16(Afh[mi], Bfl[ni], acc[mi][ni], 0, 0, 0);
        acc[mi][ni] = __builtin_amdgcn_mfma_f32_16x16x32_bf16(Afh[mi], Bfh[ni], acc[mi][ni], 0, 0, 0);
      }
  }
  float* Cd = uv + (size_t)zk * (256 * 1024);
#pragma unroll
  for (int mi = 0; mi < 2; ++mi)
#pragma unroll
    for (int ni = 0; ni < 2; ++ni) {
      const int row0 = m0 + wm * 32 + mi * 16 + ((lane >> 4) << 2);
      const int col = n0 + wn * 32 + ni * 16 + fr;
#pragma unroll
      for (int r = 0; r < 4; ++r)
        Cd[(size_t)(row0 + r) * 1024 + col] = acc[mi][ni][r];
    }
}

// ================= attention mix per (asym, b) =================
__global__ __launch_bounds__(256) void attn_mix(
    const float* __restrict__ WyY, const float* __restrict__ WhY2,
    const float* __restrict__ uv, const us* __restrict__ Yh,
    const float* __restrict__ wvp, const int* __restrict__ s1, const int* __restrict__ s2,
    u32* __restrict__ rq, float* __restrict__ rfin, int t) {
  const int a = blockIdx.y, b = blockIdx.x, tid = threadIdx.x;
  const int wvi = tid >> 6, lane = tid & 63;
  const int p = a * NB + b;
  __shared__ float4 u4s[128], w4s[128];
  __shared__ float s_sh[NT], al_sh[NT];
  const float* uv0 = uv + (size_t)p * 1024;
  const float* uv1 = uv + 256 * 1024 + (size_t)p * 1024;
  if (tid < 128) {
    const float4 x = ld4(WhY2 + ((size_t)p * NT + t) * NH + tid * 4);
    const float4 y0 = ld4(uv0 + tid * 4);
    const float4 y1 = ld4(uv1 + tid * 4);
    u4s[tid] = make_float4(x.x + y0.x + y1.x, x.y + y0.y + y1.y,
                           x.z + y0.z + y1.z, x.w + y0.w + y1.w);
    w4s[tid] = ld4(wvp + tid * 4);
  }
  __syncthreads();
  const int sl = (a ? s2 : s1)[b];
  const float* wyb = WyY + (size_t)p * NT * NH;
  for (int tp = wvi; tp < NT; tp += 4) {
    float pt = 0.f;
    if (tp < sl) {
      const float* row = wyb + (size_t)tp * NH;
#pragma unroll
      for (int j2 = 0; j2 < 2; ++j2) {
        const int j = lane + (j2 << 6);
        const float4 x = ld4(row + j * 4);
        const float4 u = u4s[j], ww = w4s[j];
        pt += tanh_fast(x.x + u.x) * ww.x + tanh_fast(x.y + u.y) * ww.y
            + tanh_fast(x.z + u.z) * ww.z + tanh_fast(x.w + u.w) * ww.w;
      }
      for (int off = 32; off; off >>= 1) pt += __shfl_xor(pt, off, 64);
    }
    if (lane == 0) s_sh[tp] = (tp < sl) ? pt : -1e30f;
  }
  __syncthreads();
  if (tid < NT) {
    const float sv = s_sh[tid];
    float mx = sv;
    for (int off = 32; off; off >>= 1) mx = fmaxf(mx, __shfl_xor(mx, off, 64));
    const float e = (tid < sl) ? __expf(sv - mx) : 0.f;
    float sm = e;
    for (int off = 32; off; off >>= 1) sm += __shfl_xor(sm, off, 64);
    al_sh[tid] = e / sm;
  }
  __syncthreads();
  // Y @ alpha : thread owns h-cols {2tid, 2tid+1} (u32 = 2 packed bf16)
  const u32* Yp32 = (const u32*)(Yh + (size_t)((a ? 2 : 0) * NB + b) * NT * NH);
  float ya0 = 0.f, ya1 = 0.f;
  for (int tp = 0; tp < sl; ++tp) {
    const u32 yv = Yp32[tp * 256 + tid];
    const float alv = al_sh[tp];
    ya0 += alv * bf2f((us)(yv & 0xFFFF));
    ya1 += alv * bf2f((us)(yv >> 16));
  }
  const int snap = (a ? s1 : s2)[b] - 1;
  const int h0 = tid * 2;
  const float rn0 = ya0 + tanh_fast(uv0[NH + h0] + uv1[NH + h0]);
  const float rn1 = ya1 + tanh_fast(uv0[NH + h0 + 1] + uv1[NH + h0 + 1]);
  u32* rwr = rq + (size_t)(t & 1) * (256 * NH);
  const us r0h = f2bf(rn0), r1h = f2bf(rn1);
  rwr[(size_t)p * NH + h0] = (((u32)r0h) << 16) | f2bf(rn0 - bf2f(r0h));
  rwr[(size_t)p * NH + h0 + 1] = (((u32)r1h) << 16) | f2bf(rn1 - bf2f(r1h));
  if (t == snap) {
    rfin[(size_t)p * NH + h0] = rn0;
    rfin[(size_t)p * NH + h0 + 1] = rn1;
  }
}

// ================= WyY / WhY2 (parallel, once) =================
__global__ __launch_bounds__(256) void gemm_yw(
    const us* __restrict__ Yh, const us* __restrict__ Yl,
    const us* __restrict__ Wyh, const us* __restrict__ Wyl,
    const us* __restrict__ Whh, const us* __restrict__ Whl,
    float* __restrict__ WyY, float* __restrict__ WhY2) {
  const int n0 = blockIdx.x << 6, m0 = blockIdx.y << 6, z = blockIdx.z;
  const int runsel = (z == 0) ? 0 : (z == 1) ? 2 : (z == 2) ? 1 : 3;
  const us* Bh = (z < 2) ? Wyh : Whh;
  const us* Bl = (z < 2) ? Wyl : Whl;
  float* Cd = (z < 2) ? (WyY + (size_t)z * (NB * NT * NH)) : (WhY2 + (size_t)(z - 2) * (NB * NT * NH));
  const int tid = threadIdx.x;
  const int wave = tid >> 6, lane = tid & 63;
  const int wm = wave >> 1, wn = wave & 1;
  const int fr = lane & 15, kg = (lane >> 4) << 3;
  __shared__ __align__(16) us As[2][64][40];
  __shared__ __align__(16) us Bs[2][64][40];
  const int sr = tid >> 2, sq = tid & 3;
  f32x4 acc[2][2];
#pragma unroll
  for (int mi = 0; mi < 2; ++mi)
#pragma unroll
    for (int ni = 0; ni < 2; ++ni) acc[mi][ni] = 0.f;
  const size_t arow = (size_t)runsel * (NB * NT) + m0 + sr;
  for (int ch = 0; ch < 16; ++ch) {
    const int k8 = (ch << 5) + (sq << 3);
    const bf16x8 ah = *(const bf16x8*)&Yh[arow * NH + k8];
    const bf16x8 al = *(const bf16x8*)&Yl[arow * NH + k8];
    const bf16x8 bh = *(const bf16x8*)&Bh[(size_t)(n0 + sr) * NH + k8];
    const bf16x8 bl = *(const bf16x8*)&Bl[(size_t)(n0 + sr) * NH + k8];
    __syncthreads();
    *(bf16x8*)&As[0][sr][sq << 3] = ah;
    *(bf16x8*)&As[1][sr][sq << 3] = al;
    *(bf16x8*)&Bs[0][sr][sq << 3] = bh;
    *(bf16x8*)&Bs[1][sr][sq << 3] = bl;
    __syncthreads();
    bf16x8 Afh[2], Afl[2], Bfh[2], Bfl[2];
#pragma unroll
    for (int mi = 0; mi < 2; ++mi) {
      Afh[mi] = *(const bf16x8*)&As[0][wm * 32 + mi * 16 + fr][kg];
      Afl[mi] = *(const bf16x8*)&As[1][wm * 32 + mi * 16 + fr][kg];
    }
#pragma unroll
    for (int ni = 0; ni < 2; ++ni) {
      Bfh[ni] = *(const bf16x8*)&Bs[0][wn * 32 + ni * 16 + fr][kg];
      Bfl[ni] = *(const bf16x8*)&Bs[1][wn * 32 + ni * 16 + fr][kg];
    }
#pragma unroll
    for (int mi = 0; mi < 2; ++mi)
#pragma unroll
      for (int ni = 0; ni < 2; ++ni) {
        acc[mi][ni] = __builtin_amdgcn_mfma_f32_16x16x32_bf16(Afl[mi], Bfh[ni], acc[mi][ni], 0, 0, 0);
        acc[mi][ni] = __builtin_amdgcn_mfma_f32_16x16x32_bf16(Afh[mi], Bfl[ni], acc[mi][ni], 0, 0, 0);
        acc[mi][ni] = __builtin_amdgcn_mfma_f32_16x16x32_bf16(Afh[mi], Bfh[ni], acc[mi][ni], 0, 0, 0);
      }
  }
#pragma unroll
  for (int mi = 0; mi < 2; ++mi)
#pragma unroll
    for (int ni = 0; ni < 2; ++ni) {
      const int row0 = m0 + wm * 32 + mi * 16 + ((lane >> 4) << 2);
      const int col = n0 + wn * 32 + ni * 16 + fr;
#pragma unroll
      for (int r = 0; r < 4; ++r)
        Cd[(size_t)(row0 + r) * NH + col] = acc[mi][ni][r];
    }
}

// ================= la/lb = tanh([rfin | last_h] @ [Wp;Wx]) =================
__global__ __launch_bounds__(256) void gemm_fin(
    const float* __restrict__ rfin, const u32* __restrict__ hq1,
    const us* __restrict__ Wpxh, const us* __restrict__ Wpxl,
    float* __restrict__ lalb) {
  const int n0 = blockIdx.x << 6, m0 = blockIdx.y << 6;
  const int tid = threadIdx.x;
  const int wave = tid >> 6, lane = tid & 63;
  const int wm = wave >> 1, wn = wave & 1;
  const int fr = lane & 15, kg = (lane >> 4) << 3;
  __shared__ __align__(16) us As[2][64][40];
  __shared__ __align__(16) us Bs[2][64][40];
  const int sr = tid >> 2, sq = tid & 3;
  const int r_g = m0 + sr;
  const int run = r_g >> 7, bb = r_g & 127;
  f32x4 acc[2][2];
#pragma unroll
  for (int mi = 0; mi < 2; ++mi)
#pragma unroll
    for (int ni = 0; ni < 2; ++ni) acc[mi][ni] = 0.f;
  for (int ch = 0; ch < 32; ++ch) {
    const int k8 = (ch << 5) + (sq << 3);
    bf16x8 ah, al;
    if (k8 < NH) {
      const float4 v1 = ld4(rfin + (size_t)r_g * NH + k8);
      const float4 v2 = ld4(rfin + (size_t)r_g * NH + k8 + 4);
      float va[8] = {v1.x, v1.y, v1.z, v1.w, v2.x, v2.y, v2.z, v2.w};
#pragma unroll
      for (int u = 0; u < 8; ++u) {
        const us hh = f2bf(va[u]);
        ah[u] = (short)hh;
        al[u] = (short)f2bf(va[u] - bf2f(hh));
      }
    } else {
      const u32* hp = hq1 + (size_t)((run ? 3 : 1) * NB + bb) * NH + (k8 - NH);
#pragma unroll
      for (int u = 0; u < 8; ++u) {
        const u32 pv = hp[u];
        ah[u] = (short)(pv >> 16);
        al[u] = (short)(pv & 0xFFFF);
      }
    }
    const bf16x8 bh = *(const bf16x8*)&Wpxh[(size_t)(n0 + sr) * 1024 + k8];
    const bf16x8 bl = *(const bf16x8*)&Wpxl[(size_t)(n0 + sr) * 1024 + k8];
    __syncthreads();
    *(bf16x8*)&As[0][sr][sq << 3] = ah;
    *(bf16x8*)&As[1][sr][sq << 3] = al;
    *(bf16x8*)&Bs[0][sr][sq << 3] = bh;
    *(bf16x8*)&Bs[1][sr][sq << 3] = bl;
    __syncthreads();
    bf16x8 Afh[2], Afl[2], Bfh[2], Bfl[2];
#pragma unroll
    for (int mi = 0; mi < 2; ++mi) {
      Afh[mi] = *(const bf16x8*)&As[0][wm * 32 + mi * 16 + fr][kg];
      Afl[mi] = *(const bf16x8*)&As[1][wm * 32 + mi * 16 + fr][kg];
    }
#pragma unroll
    for (int ni = 0; ni < 2; ++ni) {
      Bfh[ni] = *(const bf16x8*)&Bs[0][wn * 32 + ni * 16 + fr][kg];
      Bfl[ni] = *(const bf16x8*)&Bs[1][wn * 32 + ni * 16 + fr][kg];
    }
#pragma unroll
    for (int mi = 0; mi < 2; ++mi)
#pragma unroll
      for (int ni = 0; ni < 2; ++ni) {
        acc[mi][ni] = __builtin_amdgcn_mfma_f32_16x16x32_bf16(Afl[mi], Bfh[ni], acc[mi][ni], 0, 0, 0);
        acc[mi][ni] = __builtin_amdgcn_mfma_f32_16x16x32_bf16(Afh[mi], Bfl[ni], acc[mi][ni], 0, 0, 0);
        acc[mi][ni] = __builtin_amdgcn_mfma_f32_16x16x32_bf16(Afh[mi], Bfh[ni], acc[mi][ni], 0, 0, 0);
      }
  }
#pragma unroll
  for (int mi = 0; mi < 2; ++mi)
#pragma unroll
    for (int ni = 0; ni < 2; ++ni) {
      const int row0 = m0 + wm * 32 + mi * 16 + ((lane >> 4) << 2);
      const int col = n0 + wn * 32 + ni * 16 + fr;
#pragma unroll
      for (int r = 0; r < 4; ++r)
        lalb[(size_t)(row0 + r) * NH + col] = tanh_fast(acc[mi][ni][r]);
    }
}

// ================= pack: bf16 hi/lo splits =================
__global__ void pack_k(
    const float* __restrict__ W1, const float* __restrict__ W2,
    const float* __restrict__ Wy, const float* __restrict__ Wh,
    const float* __restrict__ Wr, const float* __restrict__ Wt,
    const float* __restrict__ Wp, const float* __restrict__ Wx,
    us* W1h, us* W1l, us* W2h, us* W2l,
    us* Wyh, us* Wyl, us* Whh, us* Whl,
    us* Wrth, us* Wrtl, us* Wpxh, us* Wpxl) {
  const int idx = blockIdx.x * 256 + threadIdx.x;
  const int SZW = 2048 * 832, SZS = 512 * 512, SZR = 1024 * 512;
  float v = 0.f; us *dh, *dl; int di;
  if (idx < 2 * SZW) {
    const float* W = (idx < SZW) ? W1 : W2;
    di = (idx < SZW) ? idx : idx - SZW;
    const int col = di / 832, k = di % 832;
    const int g = (col & 63) >> 4;
    const int gh = (col >> 6) * 16 + (col & 15);
    const int srcc = g * NH + gh;          // gate-interleaved, 16-h groups
    if (k < ND) v = W[(size_t)k * 2048 + srcc];
    else if (k >= 320) v = W[(size_t)(k - 20) * 2048 + srcc];
    dh = (idx < SZW) ? W1h : W2h; dl = (idx < SZW) ? W1l : W2l;
  } else if (idx < 2 * SZW + 2 * SZS) {
    const int i2 = idx - 2 * SZW;
    const float* W = (i2 < SZS) ? Wy : Wh;
    di = (i2 < SZS) ? i2 : i2 - SZS;
    const int n = di >> 9, k = di & 511;
    v = W[(size_t)k * NH + n];
    dh = (i2 < SZS) ? Wyh : Whh; dl = (i2 < SZS) ? Wyl : Whl;
  } else if (idx < 2 * SZW + 2 * SZS + SZR) {
    di = idx - 2 * SZW - 2 * SZS;
    const int n = di >> 9, k = di & 511;
    v = (n < NH) ? Wr[(size_t)k * NH + n] : Wt[(size_t)k * NH + (n - NH)];
    dh = Wrth; dl = Wrtl;
  } else {
    di = idx - 2 * SZW - 2 * SZS - SZR;
    const int n = di >> 10, k = di & 1023;
    v = (k < NH) ? Wp[(size_t)k * NH + n] : Wx[(size_t)(k - NH) * NH + n];
    dh = Wpxh; dl = Wpxl;
  }
  const us h = f2bf(v);
  dh[di] = h;
  dl[di] = f2bf(v - bf2f(h));
}

__global__ void out_k(const float* __restrict__ lalb, const float* __restrict__ U,
                      const float* __restrict__ bU, float* __restrict__ out) {
  const int tid = threadIdx.x;
  const int b = tid >> 1, j = tid & 1;
  float s = bU[j];
  for (int h = 0; h < NH; ++h)
    s += (lalb[b * NH + h] + lalb[NB * NH + b * NH + h]) * U[h * 2 + j];
  out[b * 2 + j] = s;
}

extern "C" void kernel_launch(void* const* d_in, const int* in_sizes, int n_in,
                              void* d_out, int out_size, void* d_ws, size_t ws_size,
                              hipStream_t stream) {
  const int* tok1 = (const int*)d_in[0];
  const int* tok2 = (const int*)d_in[1];
  const int* s1   = (const int*)d_in[2];
  const int* s2   = (const int*)d_in[3];
  const float* emb = (const float*)d_in[4];
  const float* W1 = (const float*)d_in[5];
  const float* b1 = (const float*)d_in[6];
  const float* W2 = (const float*)d_in[7];
  const float* b2 = (const float*)d_in[8];
  const float* Wy = (const float*)d_in[9];
  const float* Wh = (const float*)d_in[10];
  const float* Wr = (const float*)d_in[11];
  const float* wv = (const float*)d_in[12];
  const float* Wt = (const float*)d_in[13];
  const float* Wp = (const float*)d_in[14];
  const float* Wx = (const float*)d_in[15];
  const float* U  = (const float*)d_in[16];
  const float* bU = (const float*)d_in[17];

  u32* wsu = (u32*)d_ws;
  u32* hq   = wsu;                          // 2 x 4*128*512
  u32* rq   = hq + 524288;                  // 2 x 256*512
  float* cbuf = (float*)(rq + 262144);      // 4*128*512
  float* uv   = cbuf + 262144;              // 2 x 256*1024
  float* rfin = uv + 524288;                // 256*512
  float* lalb = rfin + 131072;              // 256*512
  float* WyY  = lalb + 131072;              // 2*128*64*512
  float* WhY2 = WyY + 8388608;
  us* Yh = (us*)(WhY2 + 8388608);           // 4*128*64*512
  us* Yl = Yh + 16777216;
  us* W1h = Yl + 16777216;                  // 2048*832 each
  us* W1l = W1h + 1703936;
  us* W2h = W1l + 1703936;
  us* W2l = W2h + 1703936;
  us* Wyh = W2l + 1703936;                  // 512*512 each
  us* Wyl = Wyh + 262144;
  us* Whh = Wyl + 262144;
  us* Whl = Whh + 262144;
  us* Wrth = Whl + 262144;                  // 1024*512 each
  us* Wrtl = Wrth + 524288;
  us* Wpxh = Wrtl + 524288;                 // 512*1024 each
  us* Wpxl = Wpxh + 524288;

  // zero h/r state + c
  hipMemsetAsync(d_ws, 0, 1048576ull * 4, stream);
  pack_k<<<19456, 256, 0, stream>>>(W1, W2, Wy, Wh, Wr, Wt, Wp, Wx,
                                    W1h, W1l, W2h, W2l, Wyh, Wyl, Whh, Whl,
                                    Wrth, Wrtl, Wpxh, Wpxl);

  for (int t = 0; t < NT; ++t)
    lstm_step<<<256, 256, 0, stream>>>(emb, tok1, tok2, W1h, W1l, W2h, W2l,
                                       b1, b2, s1, s2, hq, cbuf, Yh, Yl, t);

  gemm_yw<<<dim3(8, 128, 4), 256, 0, stream>>>(Yh, Yl, Wyh, Wyl, Whh, Whl, WyY, WhY2);

  for (int t = 0; t < NT; ++t) {
    uv_gemm<<<128, 256, 0, stream>>>(Wrth, Wrtl, rq, uv, t);
    attn_mix<<<dim3(NB, 2), 256, 0, stream>>>(WyY, WhY2, uv, Yh, wv, s1, s2, rq, rfin, t);
  }

  gemm_fin<<<dim3(8, 4, 1), 256, 0, stream>>>(rfin, hq + 262144, Wpxh, Wpxl, lalb);
  out_k<<<1, 256, 0, stream>>>(lalb, U, bU, (float*)d_out);
}

// Round 5
// 3248.615 us; speedup vs baseline: 6.0569x; 1.1439x over previous
//
#include <hip/hip_runtime.h>

typedef __attribute__((ext_vector_type(8))) short bf16x8;
typedef __attribute__((ext_vector_type(4))) float f32x4;
typedef unsigned short us;
typedef unsigned int u32;

#define NB 128
#define NT 64
#define ND 300
#define NH 512
#define KW 832   // padded LSTM K: 320 (emb) + 512 (h)

__device__ __forceinline__ float4 ld4(const float* p) { return *(const float4*)p; }
__device__ __forceinline__ us f2bf(float x) {
  u32 u = __float_as_uint(x);
  u += 0x7FFF + ((u >> 16) & 1);
  return (us)(u >> 16);
}
__device__ __forceinline__ float bf2f(us h) { return __uint_as_float(((u32)h) << 16); }
__device__ __forceinline__ float tanh_fast(float x) {
  x = fminf(fmaxf(x, -15.f), 15.f);
  const float e = __expf(2.f * x);
  return (e - 1.f) / (e + 1.f);
}
__device__ __forceinline__ float sigm(float x) { return 1.f / (1.f + __expf(-x)); }

#define MFMA12(acc, Afh, Afl, Bfh, Bfl)                                                     \
  _Pragma("unroll") for (int mi = 0; mi < 2; ++mi)                                          \
  _Pragma("unroll") for (int ni = 0; ni < 2; ++ni) {                                        \
    acc[mi][ni] = __builtin_amdgcn_mfma_f32_16x16x32_bf16(Afl[mi], Bfh[ni], acc[mi][ni], 0, 0, 0); \
    acc[mi][ni] = __builtin_amdgcn_mfma_f32_16x16x32_bf16(Afh[mi], Bfl[ni], acc[mi][ni], 0, 0, 0); \
    acc[mi][ni] = __builtin_amdgcn_mfma_f32_16x16x32_bf16(Afh[mi], Bfh[ni], acc[mi][ni], 0, 0, 0); \
  }

// =============== pre-gather emb -> X bf16 hi/lo planes [2][B][T][320] ===============
__global__ __launch_bounds__(256) void gather_x(
    const float* __restrict__ emb, const int* __restrict__ tok1, const int* __restrict__ tok2,
    us* __restrict__ Xh, us* __restrict__ Xl) {
  const int gid = blockIdx.x * 256 + threadIdx.x;      // 655360 total
  const int g = gid % 40, row = gid / 40;
  const int t = row & 63, b = (row >> 6) & 127, seq = row >> 13;
  const int token = (seq ? tok2 : tok1)[b * NT + t];
  const int k8 = g * 8;
  float va[8];
  if (k8 + 8 <= ND) {
    const float4 v1 = ld4(emb + (size_t)token * ND + k8);
    const float4 v2 = ld4(emb + (size_t)token * ND + k8 + 4);
    va[0] = v1.x; va[1] = v1.y; va[2] = v1.z; va[3] = v1.w;
    va[4] = v2.x; va[5] = v2.y; va[6] = v2.z; va[7] = v2.w;
  } else {
#pragma unroll
    for (int u = 0; u < 8; ++u) {
      const int k = k8 + u;
      va[u] = (k < ND) ? emb[(size_t)token * ND + k] : 0.f;
    }
  }
  bf16x8 ah, al;
#pragma unroll
  for (int u = 0; u < 8; ++u) {
    const us h = f2bf(va[u]);
    ah[u] = (short)h;
    al[u] = (short)f2bf(va[u] - bf2f(h));
  }
  const size_t o = (size_t)row * 320 + k8;
  *(bf16x8*)(Xh + o) = ah;
  *(bf16x8*)(Xl + o) = al;
}

// =============== fused LSTM step: gates GEMM + pointwise (pipelined) ===============
__global__ __launch_bounds__(256) void lstm_step(
    const us* __restrict__ Xh, const us* __restrict__ Xl,
    const us* __restrict__ W1h, const us* __restrict__ W1l,
    const us* __restrict__ W2h, const us* __restrict__ W2l,
    const float* __restrict__ b1, const float* __restrict__ b2,
    const int* __restrict__ s1, const int* __restrict__ s2,
    us* __restrict__ hqh, us* __restrict__ hql, float* __restrict__ cbuf,
    us* __restrict__ Yh, us* __restrict__ Yl, int t) {
  const int bid = blockIdx.x;
  const int nt = (bid & 7) * 4 + ((bid >> 3) & 3);
  const int mt = bid >> 5;
  const int n0 = nt << 6, m0 = mt << 6;
  const int tid = threadIdx.x;
  const int wave = tid >> 6, lane = tid & 63;
  const int wm = wave >> 1, wn = wave & 1;

  __shared__ bf16x8 Alds[2][2][256];
  __shared__ bf16x8 Blds[2][2][256];
  __shared__ float Gs[64][65];

  const int sr = tid >> 2, sq = tid & 3;
  const int sidx = ((sr >> 4) << 6) | (sq << 4) | (sr & 15);
  const int rg = m0 + sr;
  const int run = rg >> 7, bb = rg & 127;          // uniform run per block
  const int seq = (run == 0 || run == 3) ? 0 : 1;
  const us* Bh = (run & 1) ? W2h : W1h;
  const us* Bl = (run & 1) ? W2l : W1l;
  const size_t xrow = ((size_t)(seq * NB + bb) * NT + t) * 320;
  const size_t hrow = (size_t)(run * NB + bb) * NH;
  const us* hrh = hqh + (size_t)((t + 1) & 1) * (4 * NB * NH);
  const us* hrl = hql + (size_t)((t + 1) & 1) * (4 * NB * NH);
  const size_t brow = (size_t)(n0 + sr) * KW;

  f32x4 acc[2][2];
#pragma unroll
  for (int mi = 0; mi < 2; ++mi)
#pragma unroll
    for (int ni = 0; ni < 2; ++ni) acc[mi][ni] = 0.f;

  bf16x8 ah, al, bh, bl;
  {
    const int k8 = sq << 3;
    ah = *(const bf16x8*)(Xh + xrow + k8);
    al = *(const bf16x8*)(Xl + xrow + k8);
    bh = *(const bf16x8*)(Bh + brow + k8);
    bl = *(const bf16x8*)(Bl + brow + k8);
  }
  Alds[0][0][sidx] = ah; Alds[0][1][sidx] = al;
  Blds[0][0][sidx] = bh; Blds[0][1][sidx] = bl;

  for (int ch = 0; ch < 26; ++ch) {
    const int cur = ch & 1;
    __syncthreads();
    const bool more = ch < 25;
    if (more) {
      const int k8 = ((ch + 1) << 5) + (sq << 3);
      if (k8 < 320) {
        ah = *(const bf16x8*)(Xh + xrow + k8);
        al = *(const bf16x8*)(Xl + xrow + k8);
      } else {
        ah = *(const bf16x8*)(hrh + hrow + (k8 - 320));
        al = *(const bf16x8*)(hrl + hrow + (k8 - 320));
      }
      bh = *(const bf16x8*)(Bh + brow + k8);
      bl = *(const bf16x8*)(Bl + brow + k8);
    }
    bf16x8 Afh[2], Afl[2], Bfh[2], Bfl[2];
#pragma unroll
    for (int mi = 0; mi < 2; ++mi) {
      Afh[mi] = Alds[cur][0][(wm * 2 + mi) * 64 + lane];
      Afl[mi] = Alds[cur][1][(wm * 2 + mi) * 64 + lane];
    }
#pragma unroll
    for (int ni = 0; ni < 2; ++ni) {
      Bfh[ni] = Blds[cur][0][(wn * 2 + ni) * 64 + lane];
      Bfl[ni] = Blds[cur][1][(wn * 2 + ni) * 64 + lane];
    }
    MFMA12(acc, Afh, Afl, Bfh, Bfl)
    if (more) {
      Alds[cur ^ 1][0][sidx] = ah; Alds[cur ^ 1][1][sidx] = al;
      Blds[cur ^ 1][0][sidx] = bh; Blds[cur ^ 1][1][sidx] = bl;
    }
  }

  // gates -> LDS
  const int fr = lane & 15;
#pragma unroll
  for (int mi = 0; mi < 2; ++mi)
#pragma unroll
    for (int ni = 0; ni < 2; ++ni) {
      const int r0 = wm * 32 + mi * 16 + ((lane >> 4) << 2);
      const int cc = wn * 32 + ni * 16 + fr;
#pragma unroll
      for (int r = 0; r < 4; ++r) Gs[r0 + r][cc] = acc[mi][ni][r];
    }
  __syncthreads();

  // fused pointwise update: thread (ur, hg) -> 4 h-cols
  const int ur = tid & 63, hg = tid >> 6;
  const int gu = m0 + ur;
  const int runU = gu >> 7, bU = gu & 127;
  const int slU = ((runU == 0 || runU == 3) ? s1 : s2)[bU];
  const float* bias = (runU & 1) ? b2 : b1;
  const bool vld = t < slU;
  us* hwh = hqh + (size_t)(t & 1) * (4 * NB * NH);
  us* hwl = hql + (size_t)(t & 1) * (4 * NB * NH);

  const int hcb = hg << 2;
  const int ghb = nt * 16 + hcb;
  const size_t so = (size_t)(runU * NB + bU) * NH + ghb;
  const float4 bi4 = ld4(bias + ghb);
  const float4 bj4 = ld4(bias + NH + ghb);
  const float4 bf4 = ld4(bias + 2 * NH + ghb);
  const float4 bo4 = ld4(bias + 3 * NH + ghb);
  const float4 c4 = ld4(cbuf + so);
  const uint2 hh2 = *(const uint2*)(hrh + so);
  const uint2 hl2 = *(const uint2*)(hrl + so);
  const float bia[4] = {bi4.x, bi4.y, bi4.z, bi4.w};
  const float bja[4] = {bj4.x, bj4.y, bj4.z, bj4.w};
  const float bfa[4] = {bf4.x, bf4.y, bf4.z, bf4.w};
  const float boa[4] = {bo4.x, bo4.y, bo4.z, bo4.w};
  const float ca[4] = {c4.x, c4.y, c4.z, c4.w};
  const us hpo[4] = {(us)(hh2.x & 0xFFFF), (us)(hh2.x >> 16), (us)(hh2.y & 0xFFFF), (us)(hh2.y >> 16)};
  const us lpo[4] = {(us)(hl2.x & 0xFFFF), (us)(hl2.x >> 16), (us)(hl2.y & 0xFFFF), (us)(hl2.y >> 16)};
  float cw[4]; us hh4[4], hl4[4], yh4[4], yl4[4];
#pragma unroll
  for (int e = 0; e < 4; ++e) {
    const int hc = hcb + e;
    const float gi = Gs[ur][hc] + bia[e];
    const float gj = Gs[ur][16 + hc] + bja[e];
    const float gf = Gs[ur][32 + hc] + bfa[e];
    const float go = Gs[ur][48 + hc] + boa[e];
    const float hold = bf2f(hpo[e]) + bf2f(lpo[e]);
    const float cn = ca[e] * sigm(gf + 1.f) + sigm(gi) * tanh_fast(gj);
    const float hn = tanh_fast(cn) * sigm(go);
    cw[e] = vld ? cn : ca[e];
    const float hval = vld ? hn : hold;
    const float y = vld ? hn : 0.f;
    hh4[e] = f2bf(hval);
    hl4[e] = f2bf(hval - bf2f(hh4[e]));
    yh4[e] = f2bf(y);
    yl4[e] = f2bf(y - bf2f(yh4[e]));
  }
  *(float4*)(cbuf + so) = make_float4(cw[0], cw[1], cw[2], cw[3]);
  *(uint2*)(hwh + so) = make_uint2((u32)hh4[0] | ((u32)hh4[1] << 16), (u32)hh4[2] | ((u32)hh4[3] << 16));
  *(uint2*)(hwl + so) = make_uint2((u32)hl4[0] | ((u32)hl4[1] << 16), (u32)hl4[2] | ((u32)hl4[3] << 16));
  const size_t yi = ((size_t)(runU * NB + bU) * NT + t) * NH + ghb;
  *(uint2*)(Yh + yi) = make_uint2((u32)yh4[0] | ((u32)yh4[1] << 16), (u32)yh4[2] | ((u32)yh4[3] << 16));
  *(uint2*)(Yl + yi) = make_uint2((u32)yl4[0] | ((u32)yl4[1] << 16), (u32)yl4[2] | ((u32)yl4[3] << 16));
}

// =============== uv = r @ [Wr|Wt], k-split x4, pipelined ===============
__global__ __launch_bounds__(256) void uv_gemm(
    const us* __restrict__ Wrth, const us* __restrict__ Wrtl,
    const us* __restrict__ rqh, const us* __restrict__ rql,
    float* __restrict__ uv, int t) {
  const int bid = blockIdx.x;
  const int zk = bid >> 6, rem = bid & 63;
  const int nt = rem & 15, mt = rem >> 4;
  const int n0 = nt << 6, m0 = mt << 6;
  const int tid = threadIdx.x;
  const int wave = tid >> 6, lane = tid & 63;
  const int wm = wave >> 1, wn = wave & 1;

  __shared__ bf16x8 Alds[2][2][256];
  __shared__ bf16x8 Blds[2][2][256];

  const int sr = tid >> 2, sq = tid & 3;
  const int sidx = ((sr >> 4) << 6) | (sq << 4) | (sr & 15);
  const us* rrh = rqh + (size_t)((t + 1) & 1) * (256 * NH);
  const us* rrl = rql + (size_t)((t + 1) & 1) * (256 * NH);
  const size_t arow = (size_t)(m0 + sr) * NH;
  const size_t brow = (size_t)(n0 + sr) * NH;

  f32x4 acc[2][2];
#pragma unroll
  for (int mi = 0; mi < 2; ++mi)
#pragma unroll
    for (int ni = 0; ni < 2; ++ni) acc[mi][ni] = 0.f;

  bf16x8 ah, al, bh, bl;
  {
    const int k8 = (zk << 7) + (sq << 3);
    ah = *(const bf16x8*)(rrh + arow + k8);
    al = *(const bf16x8*)(rrl + arow + k8);
    bh = *(const bf16x8*)(Wrth + brow + k8);
    bl = *(const bf16x8*)(Wrtl + brow + k8);
  }
  Alds[0][0][sidx] = ah; Alds[0][1][sidx] = al;
  Blds[0][0][sidx] = bh; Blds[0][1][sidx] = bl;

  for (int ch = 0; ch < 4; ++ch) {
    const int cur = ch & 1;
    __syncthreads();
    const bool more = ch < 3;
    if (more) {
      const int k8 = (zk << 7) + ((ch + 1) << 5) + (sq << 3);
      ah = *(const bf16x8*)(rrh + arow + k8);
      al = *(const bf16x8*)(rrl + arow + k8);
      bh = *(const bf16x8*)(Wrth + brow + k8);
      bl = *(const bf16x8*)(Wrtl + brow + k8);
    }
    bf16x8 Afh[2], Afl[2], Bfh[2], Bfl[2];
#pragma unroll
    for (int mi = 0; mi < 2; ++mi) {
      Afh[mi] = Alds[cur][0][(wm * 2 + mi) * 64 + lane];
      Afl[mi] = Alds[cur][1][(wm * 2 + mi) * 64 + lane];
    }
#pragma unroll
    for (int ni = 0; ni < 2; ++ni) {
      Bfh[ni] = Blds[cur][0][(wn * 2 + ni) * 64 + lane];
      Bfl[ni] = Blds[cur][1][(wn * 2 + ni) * 64 + lane];
    }
    MFMA12(acc, Afh, Afl, Bfh, Bfl)
    if (more) {
      Alds[cur ^ 1][0][sidx] = ah; Alds[cur ^ 1][1][sidx] = al;
      Blds[cur ^ 1][0][sidx] = bh; Blds[cur ^ 1][1][sidx] = bl;
    }
  }
  float* Cd = uv + (size_t)zk * (256 * 1024);
  const int fr = lane & 15;
#pragma unroll
  for (int mi = 0; mi < 2; ++mi)
#pragma unroll
    for (int ni = 0; ni < 2; ++ni) {
      const int row0 = m0 + wm * 32 + mi * 16 + ((lane >> 4) << 2);
      const int col = n0 + wn * 32 + ni * 16 + fr;
#pragma unroll
      for (int r = 0; r < 4; ++r)
        Cd[(size_t)(row0 + r) * 1024 + col] = acc[mi][ni][r];
    }
}

// =============== attention mix per (asym, b) ===============
__global__ __launch_bounds__(256) void attn_mix(
    const float* __restrict__ WyY, const float* __restrict__ WhY2,
    const float* __restrict__ uv, const us* __restrict__ Yh,
    const float* __restrict__ wvp, const int* __restrict__ s1, const int* __restrict__ s2,
    us* __restrict__ rqh, us* __restrict__ rql, float* __restrict__ rfin, int t) {
  const int a = blockIdx.y, b = blockIdx.x, tid = threadIdx.x;
  const int wvi = tid >> 6, lane = tid & 63;
  const int p = a * NB + b;
  __shared__ float4 u4s[128], w4s[128];
  __shared__ float s_sh[NT], al_sh[NT];
  if (tid < 128) {
    const float4 x = ld4(WhY2 + ((size_t)p * NT + t) * NH + tid * 4);
    float4 s = x;
#pragma unroll
    for (int zk = 0; zk < 4; ++zk) {
      const float4 y = ld4(uv + (size_t)zk * (256 * 1024) + (size_t)p * 1024 + tid * 4);
      s.x += y.x; s.y += y.y; s.z += y.z; s.w += y.w;
    }
    u4s[tid] = s;
    w4s[tid] = ld4(wvp + tid * 4);
  }
  __syncthreads();
  const int sl = (a ? s2 : s1)[b];
  const float* wyb = WyY + (size_t)p * NT * NH;
#pragma unroll 4
  for (int tp = wvi; tp < NT; tp += 4) {
    const float* row = wyb + (size_t)tp * NH;
    float pt = 0.f;
#pragma unroll
    for (int j2 = 0; j2 < 2; ++j2) {
      const int j = lane + (j2 << 6);
      const float4 x = ld4(row + j * 4);
      const float4 u = u4s[j], ww = w4s[j];
      pt += tanh_fast(x.x + u.x) * ww.x + tanh_fast(x.y + u.y) * ww.y
          + tanh_fast(x.z + u.z) * ww.z + tanh_fast(x.w + u.w) * ww.w;
    }
    for (int off = 32; off; off >>= 1) pt += __shfl_xor(pt, off, 64);
    if (lane == 0) s_sh[tp] = (tp < sl) ? pt : -1e30f;
  }
  __syncthreads();
  if (tid < NT) {
    const float sv = s_sh[tid];
    float mx = sv;
    for (int off = 32; off; off >>= 1) mx = fmaxf(mx, __shfl_xor(mx, off, 64));
    const float e = (tid < sl) ? __expf(sv - mx) : 0.f;
    float sm = e;
    for (int off = 32; off; off >>= 1) sm += __shfl_xor(sm, off, 64);
    al_sh[tid] = e / sm;
  }
  __syncthreads();
  const u32* Yp32 = (const u32*)(Yh + (size_t)((a ? 2 : 0) * NB + b) * NT * NH);
  float ya0 = 0.f, ya1 = 0.f;
#pragma unroll 4
  for (int tp = 0; tp < sl; ++tp) {
    const u32 yv = Yp32[tp * 256 + tid];
    const float alv = al_sh[tp];
    ya0 += alv * bf2f((us)(yv & 0xFFFF));
    ya1 += alv * bf2f((us)(yv >> 16));
  }
  float uwt0 = 0.f, uwt1 = 0.f;
  const int h0 = tid * 2;
#pragma unroll
  for (int zk = 0; zk < 4; ++zk) {
    const float* up = uv + (size_t)zk * (256 * 1024) + (size_t)p * 1024 + NH + h0;
    uwt0 += up[0]; uwt1 += up[1];
  }
  const int snap = (a ? s1 : s2)[b] - 1;
  const float rn0 = ya0 + tanh_fast(uwt0);
  const float rn1 = ya1 + tanh_fast(uwt1);
  us* rwh = rqh + (size_t)(t & 1) * (256 * NH);
  us* rwl = rql + (size_t)(t & 1) * (256 * NH);
  const us r0h = f2bf(rn0), r1h = f2bf(rn1);
  const us r0l = f2bf(rn0 - bf2f(r0h)), r1l = f2bf(rn1 - bf2f(r1h));
  *(u32*)(rwh + (size_t)p * NH + h0) = (u32)r0h | ((u32)r1h << 16);
  *(u32*)(rwl + (size_t)p * NH + h0) = (u32)r0l | ((u32)r1l << 16);
  if (t == snap) {
    rfin[(size_t)p * NH + h0] = rn0;
    rfin[(size_t)p * NH + h0 + 1] = rn1;
  }
}

// =============== WyY / WhY2 (parallel, once, pipelined) ===============
__global__ __launch_bounds__(256) void gemm_yw(
    const us* __restrict__ Yh, const us* __restrict__ Yl,
    const us* __restrict__ Wyh, const us* __restrict__ Wyl,
    const us* __restrict__ Whh, const us* __restrict__ Whl,
    float* __restrict__ WyY, float* __restrict__ WhY2) {
  const int n0 = blockIdx.x << 6, m0 = blockIdx.y << 6, z = blockIdx.z;
  const int runsel = (z == 0) ? 0 : (z == 1) ? 2 : (z == 2) ? 1 : 3;
  const us* Bhp = (z < 2) ? Wyh : Whh;
  const us* Blp = (z < 2) ? Wyl : Whl;
  float* Cd = (z < 2) ? (WyY + (size_t)z * (NB * NT * NH)) : (WhY2 + (size_t)(z - 2) * (NB * NT * NH));
  const int tid = threadIdx.x;
  const int wave = tid >> 6, lane = tid & 63;
  const int wm = wave >> 1, wn = wave & 1;
  __shared__ bf16x8 Alds[2][2][256];
  __shared__ bf16x8 Blds[2][2][256];
  const int sr = tid >> 2, sq = tid & 3;
  const int sidx = ((sr >> 4) << 6) | (sq << 4) | (sr & 15);
  const size_t arow = ((size_t)runsel * (NB * NT) + m0 + sr) * NH;
  const size_t brow = (size_t)(n0 + sr) * NH;

  f32x4 acc[2][2];
#pragma unroll
  for (int mi = 0; mi < 2; ++mi)
#pragma unroll
    for (int ni = 0; ni < 2; ++ni) acc[mi][ni] = 0.f;

  bf16x8 ah, al, bh, bl;
  {
    const int k8 = sq << 3;
    ah = *(const bf16x8*)(Yh + arow + k8);
    al = *(const bf16x8*)(Yl + arow + k8);
    bh = *(const bf16x8*)(Bhp + brow + k8);
    bl = *(const bf16x8*)(Blp + brow + k8);
  }
  Alds[0][0][sidx] = ah; Alds[0][1][sidx] = al;
  Blds[0][0][sidx] = bh; Blds[0][1][sidx] = bl;

  for (int ch = 0; ch < 16; ++ch) {
    const int cur = ch & 1;
    __syncthreads();
    const bool more = ch < 15;
    if (more) {
      const int k8 = ((ch + 1) << 5) + (sq << 3);
      ah = *(const bf16x8*)(Yh + arow + k8);
      al = *(const bf16x8*)(Yl + arow + k8);
      bh = *(const bf16x8*)(Bhp + brow + k8);
      bl = *(const bf16x8*)(Blp + brow + k8);
    }
    bf16x8 Afh[2], Afl[2], Bfh[2], Bfl[2];
#pragma unroll
    for (int mi = 0; mi < 2; ++mi) {
      Afh[mi] = Alds[cur][0][(wm * 2 + mi) * 64 + lane];
      Afl[mi] = Alds[cur][1][(wm * 2 + mi) * 64 + lane];
    }
#pragma unroll
    for (int ni = 0; ni < 2; ++ni) {
      Bfh[ni] = Blds[cur][0][(wn * 2 + ni) * 64 + lane];
      Bfl[ni] = Blds[cur][1][(wn * 2 + ni) * 64 + lane];
    }
    MFMA12(acc, Afh, Afl, Bfh, Bfl)
    if (more) {
      Alds[cur ^ 1][0][sidx] = ah; Alds[cur ^ 1][1][sidx] = al;
      Blds[cur ^ 1][0][sidx] = bh; Blds[cur ^ 1][1][sidx] = bl;
    }
  }
  const int fr = lane & 15;
#pragma unroll
  for (int mi = 0; mi < 2; ++mi)
#pragma unroll
    for (int ni = 0; ni < 2; ++ni) {
      const int row0 = m0 + wm * 32 + mi * 16 + ((lane >> 4) << 2);
      const int col = n0 + wn * 32 + ni * 16 + fr;
#pragma unroll
      for (int r = 0; r < 4; ++r)
        Cd[(size_t)(row0 + r) * NH + col] = acc[mi][ni][r];
    }
}

// =============== la/lb = tanh([rfin | last_h] @ [Wp;Wx]) ===============
__global__ __launch_bounds__(256) void gemm_fin(
    const float* __restrict__ rfin, const us* __restrict__ hqh1, const us* __restrict__ hql1,
    const us* __restrict__ Wpxh, const us* __restrict__ Wpxl, float* __restrict__ lalb) {
  const int n0 = blockIdx.x << 6, m0 = blockIdx.y << 6;
  const int tid = threadIdx.x;
  const int wave = tid >> 6, lane = tid & 63;
  const int wm = wave >> 1, wn = wave & 1;
  __shared__ bf16x8 Alds[2][256];
  __shared__ bf16x8 Blds[2][256];
  const int sr = tid >> 2, sq = tid & 3;
  const int sidx = ((sr >> 4) << 6) | (sq << 4) | (sr & 15);
  const int r_g = m0 + sr;
  const int run = r_g >> 7, bb = r_g & 127;
  f32x4 acc[2][2];
#pragma unroll
  for (int mi = 0; mi < 2; ++mi)
#pragma unroll
    for (int ni = 0; ni < 2; ++ni) acc[mi][ni] = 0.f;
  for (int ch = 0; ch < 32; ++ch) {
    const int k8 = (ch << 5) + (sq << 3);
    bf16x8 ah, al;
    if (k8 < NH) {
      const float4 v1 = ld4(rfin + (size_t)r_g * NH + k8);
      const float4 v2 = ld4(rfin + (size_t)r_g * NH + k8 + 4);
      float va[8] = {v1.x, v1.y, v1.z, v1.w, v2.x, v2.y, v2.z, v2.w};
#pragma unroll
      for (int u = 0; u < 8; ++u) {
        const us hh = f2bf(va[u]);
        ah[u] = (short)hh;
        al[u] = (short)f2bf(va[u] - bf2f(hh));
      }
    } else {
      const size_t ho = (size_t)((run ? 3 : 1) * NB + bb) * NH + (k8 - NH);
      ah = *(const bf16x8*)(hqh1 + ho);
      al = *(const bf16x8*)(hql1 + ho);
    }
    const bf16x8 bh = *(const bf16x8*)(Wpxh + (size_t)(n0 + sr) * 1024 + k8);
    const bf16x8 bl = *(const bf16x8*)(Wpxl + (size_t)(n0 + sr) * 1024 + k8);
    __syncthreads();
    Alds[0][sidx] = ah; Alds[1][sidx] = al;
    Blds[0][sidx] = bh; Blds[1][sidx] = bl;
    __syncthreads();
    bf16x8 Afh[2], Afl[2], Bfh[2], Bfl[2];
#pragma unroll
    for (int mi = 0; mi < 2; ++mi) {
      Afh[mi] = Alds[0][(wm * 2 + mi) * 64 + lane];
      Afl[mi] = Alds[1][(wm * 2 + mi) * 64 + lane];
    }
#pragma unroll
    for (int ni = 0; ni < 2; ++ni) {
      Bfh[ni] = Blds[0][(wn * 2 + ni) * 64 + lane];
      Bfl[ni] = Blds[1][(wn * 2 + ni) * 64 + lane];
    }
    MFMA12(acc, Afh, Afl, Bfh, Bfl)
  }
  const int fr = lane & 15;
#pragma unroll
  for (int mi = 0; mi < 2; ++mi)
#pragma unroll
    for (int ni = 0; ni < 2; ++ni) {
      const int row0 = m0 + wm * 32 + mi * 16 + ((lane >> 4) << 2);
      const int col = n0 + wn * 32 + ni * 16 + fr;
#pragma unroll
      for (int r = 0; r < 4; ++r)
        lalb[(size_t)(row0 + r) * NH + col] = tanh_fast(acc[mi][ni][r]);
    }
}

// =============== pack: bf16 hi/lo splits ===============
__global__ void pack_k(
    const float* __restrict__ W1, const float* __restrict__ W2,
    const float* __restrict__ Wy, const float* __restrict__ Wh,
    const float* __restrict__ Wr, const float* __restrict__ Wt,
    const float* __restrict__ Wp, const float* __restrict__ Wx,
    us* W1h, us* W1l, us* W2h, us* W2l,
    us* Wyh, us* Wyl, us* Whh, us* Whl,
    us* Wrth, us* Wrtl, us* Wpxh, us* Wpxl) {
  const int idx = blockIdx.x * 256 + threadIdx.x;
  const int SZW = 2048 * 832, SZS = 512 * 512, SZR = 1024 * 512;
  float v = 0.f; us *dh, *dl; int di;
  if (idx < 2 * SZW) {
    const float* W = (idx < SZW) ? W1 : W2;
    di = (idx < SZW) ? idx : idx - SZW;
    const int col = di / 832, k = di % 832;
    const int g = (col & 63) >> 4;
    const int gh = (col >> 6) * 16 + (col & 15);
    const int srcc = g * NH + gh;
    if (k < ND) v = W[(size_t)k * 2048 + srcc];
    else if (k >= 320) v = W[(size_t)(k - 20) * 2048 + srcc];
    dh = (idx < SZW) ? W1h : W2h; dl = (idx < SZW) ? W1l : W2l;
  } else if (idx < 2 * SZW + 2 * SZS) {
    const int i2 = idx - 2 * SZW;
    const float* W = (i2 < SZS) ? Wy : Wh;
    di = (i2 < SZS) ? i2 : i2 - SZS;
    const int n = di >> 9, k = di & 511;
    v = W[(size_t)k * NH + n];
    dh = (i2 < SZS) ? Wyh : Whh; dl = (i2 < SZS) ? Wyl : Whl;
  } else if (idx < 2 * SZW + 2 * SZS + SZR) {
    di = idx - 2 * SZW - 2 * SZS;
    const int n = di >> 9, k = di & 511;
    v = (n < NH) ? Wr[(size_t)k * NH + n] : Wt[(size_t)k * NH + (n - NH)];
    dh = Wrth; dl = Wrtl;
  } else {
    di = idx - 2 * SZW - 2 * SZS - SZR;
    const int n = di >> 10, k = di & 1023;
    v = (k < NH) ? Wp[(size_t)k * NH + n] : Wx[(size_t)(k - NH) * NH + n];
    dh = Wpxh; dl = Wpxl;
  }
  const us h = f2bf(v);
  dh[di] = h;
  dl[di] = f2bf(v - bf2f(h));
}

__global__ void out_k(const float* __restrict__ lalb, const float* __restrict__ U,
                      const float* __restrict__ bU, float* __restrict__ out) {
  const int tid = threadIdx.x;
  const int b = tid >> 1, j = tid & 1;
  float s = bU[j];
  for (int h = 0; h < NH; ++h)
    s += (lalb[b * NH + h] + lalb[NB * NH + b * NH + h]) * U[h * 2 + j];
  out[b * 2 + j] = s;
}

extern "C" void kernel_launch(void* const* d_in, const int* in_sizes, int n_in,
                              void* d_out, int out_size, void* d_ws, size_t ws_size,
                              hipStream_t stream) {
  const int* tok1 = (const int*)d_in[0];
  const int* tok2 = (const int*)d_in[1];
  const int* s1   = (const int*)d_in[2];
  const int* s2   = (const int*)d_in[3];
  const float* emb = (const float*)d_in[4];
  const float* W1 = (const float*)d_in[5];
  const float* b1 = (const float*)d_in[6];
  const float* W2 = (const float*)d_in[7];
  const float* b2 = (const float*)d_in[8];
  const float* Wy = (const float*)d_in[9];
  const float* Wh = (const float*)d_in[10];
  const float* Wr = (const float*)d_in[11];
  const float* wv = (const float*)d_in[12];
  const float* Wt = (const float*)d_in[13];
  const float* Wp = (const float*)d_in[14];
  const float* Wx = (const float*)d_in[15];
  const float* U  = (const float*)d_in[16];
  const float* bU = (const float*)d_in[17];

  us* P = (us*)d_ws;
  us* hqh = P;               P += 524288;    // 2 dbuf x 4*128*512
  us* hql = P;               P += 524288;
  us* rqh = P;               P += 262144;    // 2 dbuf x 256*512
  us* rql = P;               P += 262144;
  float* cbuf = (float*)P;   P += 524288;    // 262144 f
  float* uv = (float*)P;     P += 2097152;   // 4 x 256*1024 f
  float* rfin = (float*)P;   P += 262144;    // 131072 f
  float* lalb = (float*)P;   P += 262144;    // 131072 f
  float* WyY = (float*)P;    P += 16777216;  // 8388608 f
  float* WhY2 = (float*)P;   P += 16777216;
  us* Xh = P;                P += 5242880;   // 2*128*64*320
  us* Xl = P;                P += 5242880;
  us* Yh = P;                P += 16777216;  // 4*128*64*512
  us* Yl = P;                P += 16777216;
  us* W1h = P;               P += 1703936;   // 2048*832
  us* W1l = P;               P += 1703936;
  us* W2h = P;               P += 1703936;
  us* W2l = P;               P += 1703936;
  us* Wyh = P;               P += 262144;
  us* Wyl = P;               P += 262144;
  us* Whh = P;               P += 262144;
  us* Whl = P;               P += 262144;
  us* Wrth = P;              P += 524288;
  us* Wrtl = P;              P += 524288;
  us* Wpxh = P;              P += 524288;
  us* Wpxl = P;              P += 524288;

  // zero h/r state planes + c (contiguous 4 MB head)
  hipMemsetAsync(d_ws, 0, 4194304ull, stream);
  pack_k<<<19456, 256, 0, stream>>>(W1, W2, Wy, Wh, Wr, Wt, Wp, Wx,
                                    W1h, W1l, W2h, W2l, Wyh, Wyl, Whh, Whl,
                                    Wrth, Wrtl, Wpxh, Wpxl);
  gather_x<<<2560, 256, 0, stream>>>(emb, tok1, tok2, Xh, Xl);

  for (int t = 0; t < NT; ++t)
    lstm_step<<<256, 256, 0, stream>>>(Xh, Xl, W1h, W1l, W2h, W2l,
                                       b1, b2, s1, s2, hqh, hql, cbuf, Yh, Yl, t);

  gemm_yw<<<dim3(8, 128, 4), 256, 0, stream>>>(Yh, Yl, Wyh, Wyl, Whh, Whl, WyY, WhY2);

  for (int t = 0; t < NT; ++t) {
    uv_gemm<<<256, 256, 0, stream>>>(Wrth, Wrtl, rqh, rql, uv, t);
    attn_mix<<<dim3(NB, 2), 256, 0, stream>>>(WyY, WhY2, uv, Yh, wv, s1, s2, rqh, rql, rfin, t);
  }

  gemm_fin<<<dim3(8, 4, 1), 256, 0, stream>>>(rfin, hqh + 262144, hql + 262144, Wpxh, Wpxl, lalb);
  out_k<<<1, 256, 0, stream>>>(lalb, U, bU, (float*)d_out);
}